// Round 7
// baseline (219.387 us; speedup 1.0000x reference)
//
#include <hip/hip_runtime.h>

#define N_NODES 50000
#define N_EDGES 800000
#define D 128
#define NBLOCKS 3125  // N_NODES / 16

typedef __attribute__((ext_vector_type(8))) short short8;
typedef __attribute__((ext_vector_type(4))) float f32x4;

__device__ __forceinline__ float bits2f(unsigned int u) {
    union { unsigned int u; float f; } c; c.u = u; return c.f;
}
__device__ __forceinline__ unsigned short f2b(float f) {
    union { float f; unsigned int u; } c; c.f = f;
    unsigned int r = c.u + 0x7fffu + ((c.u >> 16) & 1u);
    return (unsigned short)(r >> 16);
}

// ---------------- CSR build ----------------

__global__ void k_degrank(const int* __restrict__ dst, int* __restrict__ deg,
                          int* __restrict__ rank) {
    int e = blockIdx.x * blockDim.x + threadIdx.x;
    if (e < N_EDGES) rank[e] = atomicAdd(&deg[dst[e]], 1);
}

__global__ void k_scan1(const int* __restrict__ deg, int* __restrict__ rs,
                        int* __restrict__ bsum) {
    __shared__ int s[1024];
    int tid = threadIdx.x;
    int i = blockIdx.x * 1024 + tid;
    int v = (i < N_NODES) ? deg[i] : 0;
    s[tid] = v;
    __syncthreads();
    for (int off = 1; off < 1024; off <<= 1) {
        int t = (tid >= off) ? s[tid - off] : 0;
        __syncthreads();
        s[tid] += t;
        __syncthreads();
    }
    if (i < N_NODES) rs[i] = s[tid] - v;
    if (tid == 1023) bsum[blockIdx.x] = s[1023];
}

// single-wave shfl prefix scan over block sums (nb <= 64); uniform control
__global__ void k_scan2(int* __restrict__ bsum, int nb) {
    int lane = threadIdx.x;
    int v = (lane < nb) ? bsum[lane] : 0;
    int s = v;
    #pragma unroll
    for (int off = 1; off < 64; off <<= 1) {
        int t = __shfl_up(s, off, 64);
        if (lane >= off) s += t;
    }
    if (lane < nb) bsum[lane] = s - v;  // exclusive
}

__global__ void k_scan3(int* __restrict__ rs, const int* __restrict__ bsum) {
    int i = blockIdx.x * blockDim.x + threadIdx.x;
    if (i < N_NODES) rs[i] += bsum[i >> 10];
    if (i == 0) rs[N_NODES] = N_EDGES;
}

__global__ void k_fill2(const int* __restrict__ src, const int* __restrict__ dst,
                        const int* __restrict__ rs, const int* __restrict__ rank,
                        int* __restrict__ col) {
    int e = blockIdx.x * blockDim.x + threadIdx.x;
    if (e < N_EDGES) col[rs[dst[e]] + rank[e]] = src[e];
}

// ---------------- f32 -> bf16 cast ----------------

__global__ void k_cast(const float* __restrict__ x, unsigned short* __restrict__ xb) {
    int i = blockIdx.x * blockDim.x + threadIdx.x;
    if (i >= (N_NODES * D) / 4) return;
    float4 v = reinterpret_cast<const float4*>(x)[i];
    ushort4 o;
    o.x = f2b(v.x); o.y = f2b(v.y); o.z = f2b(v.z); o.w = f2b(v.w);
    reinterpret_cast<ushort4*>(xb)[i] = o;
}

// ---------------- pack weights into MFMA B-fragment order ----------------
// Bp[layer][kstep][cf][lane][i] = W[kstep*32 + 8*(lane>>4) + i][cf*16 + (lane&15)]
// kstep<4 -> w_nbr, else w_root (k offset -128).

__global__ void k_packw(const float* __restrict__ wn0, const float* __restrict__ wr0,
                        const float* __restrict__ wn1, const float* __restrict__ wr1,
                        const float* __restrict__ wn2, const float* __restrict__ wr2,
                        unsigned short* __restrict__ Bp) {
    int t = blockIdx.x * blockDim.x + threadIdx.x;
    if (t >= 3 * 8 * 8 * 64) return;
    int layer = t >> 12;
    int rem = t & 4095;
    int kstep = rem >> 9;
    int cf = (rem >> 6) & 7;
    int lane = t & 63;
    const float* wns[3] = {wn0, wn1, wn2};
    const float* wrs[3] = {wr0, wr1, wr2};
    int kb = kstep * 32 + (lane >> 4) * 8;
    int colv = cf * 16 + (lane & 15);
    const float* W = (kstep < 4) ? wns[layer] : wrs[layer];
    int koff = (kstep < 4) ? kb : kb - 128;
    unsigned short* dstp = Bp + (((layer * 64 + kstep * 8 + cf) * 64 + lane) << 3);
    #pragma unroll
    for (int i = 0; i < 8; ++i) dstp[i] = f2b(W[(koff + i) * D + colv]);
}

// ---------------- fused: mean-gather + MFMA GEMM (+relu / +cls) ----------
// 16 nodes per 256-thread block (3125 blocks -> 12500 waves, full occupancy).
// Gather: wave w aggregates nodes 4w..4w+3 with the validated agg2 pattern
// (wave-uniform shfl main loop, divergence-free direct-load remainder),
// means -> LDS rows (272 B stride: conflict-free uniform bank spread).
// MFMA: wave w computes col-frags {2w,2w+1} for all 16 rows; K=256.

#define ACCUM(v)                                                      \
    acc0 += bits2f((v).x << 16); acc1 += bits2f((v).x & 0xffff0000u); \
    acc2 += bits2f((v).y << 16); acc3 += bits2f((v).y & 0xffff0000u); \
    acc4 += bits2f((v).z << 16); acc5 += bits2f((v).z & 0xffff0000u); \
    acc6 += bits2f((v).w << 16); acc7 += bits2f((v).w & 0xffff0000u);

template <int ACT, int CLS>
__global__ __launch_bounds__(256) void k_fused(
    const unsigned short* __restrict__ Ain, const int* __restrict__ rs,
    const int* __restrict__ col, const unsigned short* __restrict__ Bp,
    const float* __restrict__ bias, unsigned short* __restrict__ outh,
    const float* __restrict__ wc, const float* __restrict__ bc,
    float* __restrict__ outf) {
    __shared__ uint4 mlds[16 * 17];   // 16 rows x 272 B = 4352 B
    __shared__ float pcls[4][16];
    const int wave = threadIdx.x >> 6;
    const int lane = threadIdx.x & 63;
    const int row0 = blockIdx.x * 16;
    const int q = lane >> 4;
    const int hl = lane & 15;
    const int d8 = hl * 8;
    char* ldsb = (char*)mlds;

    // ---- gather-mean: 4 nodes per wave ----
    for (int nn = 0; nn < 4; ++nn) {
        const int r = wave * 4 + nn;          // block-local row
        const int node = row0 + r;
        const int j0 = rs[node], j1 = rs[node + 1];
        const int deg = j1 - j0;
        int myc = (j0 + lane < j1) ? col[j0 + lane] : 0;
        const int nfull = deg < 64 ? deg : 64;
        const int niter4 = nfull >> 4;        // wave-uniform
        float acc0 = 0.f, acc1 = 0.f, acc2 = 0.f, acc3 = 0.f;
        float acc4 = 0.f, acc5 = 0.f, acc6 = 0.f, acc7 = 0.f;
        for (int i = 0; i < niter4; ++i) {    // uniform trips: shfl safe
            int t = q + (i << 4);
            int c0 = __shfl(myc, t, 64);
            int c1 = __shfl(myc, t + 4, 64);
            int c2 = __shfl(myc, t + 8, 64);
            int c3 = __shfl(myc, t + 12, 64);
            uint4 v0 = *(const uint4*)(Ain + (size_t)c0 * D + d8);
            uint4 v1 = *(const uint4*)(Ain + (size_t)c1 * D + d8);
            uint4 v2 = *(const uint4*)(Ain + (size_t)c2 * D + d8);
            uint4 v3 = *(const uint4*)(Ain + (size_t)c3 * D + d8);
            ACCUM(v0); ACCUM(v1); ACCUM(v2); ACCUM(v3);
        }
        for (int j = j0 + (niter4 << 4) + q; j < j1; j += 4) {  // no shfl here
            int c = col[j];
            uint4 v = *(const uint4*)(Ain + (size_t)c * D + d8);
            ACCUM(v);
        }
        acc0 += __shfl_xor(acc0, 16, 64); acc0 += __shfl_xor(acc0, 32, 64);
        acc1 += __shfl_xor(acc1, 16, 64); acc1 += __shfl_xor(acc1, 32, 64);
        acc2 += __shfl_xor(acc2, 16, 64); acc2 += __shfl_xor(acc2, 32, 64);
        acc3 += __shfl_xor(acc3, 16, 64); acc3 += __shfl_xor(acc3, 32, 64);
        acc4 += __shfl_xor(acc4, 16, 64); acc4 += __shfl_xor(acc4, 32, 64);
        acc5 += __shfl_xor(acc5, 16, 64); acc5 += __shfl_xor(acc5, 32, 64);
        acc6 += __shfl_xor(acc6, 16, 64); acc6 += __shfl_xor(acc6, 32, 64);
        acc7 += __shfl_xor(acc7, 16, 64); acc7 += __shfl_xor(acc7, 32, 64);
        if (lane < 16) {
            float s = 1.0f / (float)(deg > 0 ? deg : 1);
            uint4 o;
            o.x = (unsigned int)f2b(acc0 * s) | ((unsigned int)f2b(acc1 * s) << 16);
            o.y = (unsigned int)f2b(acc2 * s) | ((unsigned int)f2b(acc3 * s) << 16);
            o.z = (unsigned int)f2b(acc4 * s) | ((unsigned int)f2b(acc5 * s) << 16);
            o.w = (unsigned int)f2b(acc6 * s) | ((unsigned int)f2b(acc7 * s) << 16);
            *(uint4*)(ldsb + r * 272 + lane * 16) = o;
        }
    }
    __syncthreads();

    // ---- MFMA: wave handles col-frags 2*wave, 2*wave+1 ----
    f32x4 acc[2];
    acc[0] = (f32x4)0.0f;
    acc[1] = (f32x4)0.0f;
    const short8* bpv = reinterpret_cast<const short8*>(Bp);
    const int cf0 = wave * 2;
    #pragma unroll
    for (int kstep = 0; kstep < 8; ++kstep) {
        short8 a;
        if (kstep < 4) {
            a = *(const short8*)(ldsb + hl * 272 + kstep * 64 + q * 16);
        } else {
            a = *(const short8*)(Ain + (size_t)(row0 + hl) * D +
                                 (kstep - 4) * 32 + q * 8);
        }
        short8 b0 = bpv[(kstep * 8 + cf0) * 64 + lane];
        short8 b1 = bpv[(kstep * 8 + cf0 + 1) * 64 + lane];
        acc[0] = __builtin_amdgcn_mfma_f32_16x16x32_bf16(a, b0, acc[0], 0, 0, 0);
        acc[1] = __builtin_amdgcn_mfma_f32_16x16x32_bf16(a, b1, acc[1], 0, 0, 0);
    }

    // ---- epilogue ----
    if (CLS) {
        float p0 = 0.f, p1 = 0.f, p2 = 0.f, p3 = 0.f;
        #pragma unroll
        for (int c = 0; c < 2; ++c) {
            int bcol = (cf0 + c) * 16 + hl;
            float bv = bias[bcol];
            float wcv = wc[bcol];
            p0 += (acc[c][0] + bv) * wcv;
            p1 += (acc[c][1] + bv) * wcv;
            p2 += (acc[c][2] + bv) * wcv;
            p3 += (acc[c][3] + bv) * wcv;
        }
        #pragma unroll
        for (int m = 1; m < 16; m <<= 1) {
            p0 += __shfl_xor(p0, m, 64);
            p1 += __shfl_xor(p1, m, 64);
            p2 += __shfl_xor(p2, m, 64);
            p3 += __shfl_xor(p3, m, 64);
        }
        if (hl == 0) {
            pcls[wave][q * 4 + 0] = p0;
            pcls[wave][q * 4 + 1] = p1;
            pcls[wave][q * 4 + 2] = p2;
            pcls[wave][q * 4 + 3] = p3;
        }
        __syncthreads();
        if (threadIdx.x < 16) {
            int r = threadIdx.x;
            outf[row0 + r] = pcls[0][r] + pcls[1][r] + pcls[2][r] + pcls[3][r]
                             + bc[0];
        }
    } else {
        #pragma unroll
        for (int c = 0; c < 2; ++c) {
            int bcol = (cf0 + c) * 16 + hl;
            float bv = bias[bcol];
            #pragma unroll
            for (int i = 0; i < 4; ++i) {
                float v = acc[c][i] + bv;
                if (ACT) v = fmaxf(v, 0.f);
                outh[(size_t)(row0 + q * 4 + i) * D + bcol] = f2b(v);
            }
        }
    }
}

// ---------------- launch ----------------

extern "C" void kernel_launch(void* const* d_in, const int* in_sizes, int n_in,
                              void* d_out, int out_size, void* d_ws,
                              size_t ws_size, hipStream_t stream) {
    const float* x = (const float*)d_in[0];
    const int* ei = (const int*)d_in[1];
    const int* src = ei;
    const int* dst = ei + N_EDGES;
    const float* wn[3] = {(const float*)d_in[2], (const float*)d_in[5],
                          (const float*)d_in[8]};
    const float* wr[3] = {(const float*)d_in[3], (const float*)d_in[6],
                          (const float*)d_in[9]};
    const float* bs[3] = {(const float*)d_in[4], (const float*)d_in[7],
                          (const float*)d_in[10]};
    const float* wc = (const float*)d_in[11];
    const float* bc = (const float*)d_in[12];
    float* out = (float*)d_out;

    char* ws = (char*)d_ws;
    size_t off = 0;
    auto alloc = [&](size_t bytes) -> void* {
        void* p = (void*)(ws + off);
        off += (bytes + 255) & ~(size_t)255;
        return p;
    };
    // ~32.6 MB total. Two feature buffers ping-pong: f0 -> f1 -> f0 -> out.
    int* deg = (int*)alloc(N_NODES * 4);
    int* rs = (int*)alloc((N_NODES + 1) * 4);
    int* rank = (int*)alloc(N_EDGES * 4);
    int* bsum = (int*)alloc(64 * 4);
    int* col = (int*)alloc(N_EDGES * 4);
    unsigned short* f0 = (unsigned short*)alloc((size_t)N_NODES * D * 2);
    unsigned short* f1 = (unsigned short*)alloc((size_t)N_NODES * D * 2);
    unsigned short* Bp = (unsigned short*)alloc(3 * 256 * 128 * 2);

    hipMemsetAsync(deg, 0, N_NODES * 4, stream);

    int nb = (N_NODES + 1023) / 1024;
    k_degrank<<<(N_EDGES + 255) / 256, 256, 0, stream>>>(dst, deg, rank);
    k_scan1<<<nb, 1024, 0, stream>>>(deg, rs, bsum);
    k_scan2<<<1, 64, 0, stream>>>(bsum, nb);
    k_scan3<<<(N_NODES + 255) / 256, 256, 0, stream>>>(rs, bsum);
    k_fill2<<<(N_EDGES + 255) / 256, 256, 0, stream>>>(src, dst, rs, rank, col);

    k_cast<<<(N_NODES * D / 4 + 255) / 256, 256, 0, stream>>>(x, f0);
    k_packw<<<48, 256, 0, stream>>>(wn[0], wr[0], wn[1], wr[1], wn[2], wr[2], Bp);

    unsigned short* Bp0 = Bp;
    unsigned short* Bp1 = Bp + 256 * 128;
    unsigned short* Bp2 = Bp + 2 * 256 * 128;

    // layer 0: f0 -> f1 (relu)
    k_fused<1, 0><<<NBLOCKS, 256, 0, stream>>>(f0, rs, col, Bp0, bs[0], f1,
                                               nullptr, nullptr, nullptr);
    // layer 1: f1 -> f0 (relu)
    k_fused<1, 0><<<NBLOCKS, 256, 0, stream>>>(f1, rs, col, Bp1, bs[1], f0,
                                               nullptr, nullptr, nullptr);
    // layer 2 + classifier: f0 -> out (f32)
    k_fused<0, 1><<<NBLOCKS, 256, 0, stream>>>(f0, rs, col, Bp2, bs[2], nullptr,
                                               wc, bc, out);
}

// Round 8
// 193.963 us; speedup vs baseline: 1.1311x; 1.1311x over previous
//
#include <hip/hip_runtime.h>

#define N_NODES 50000
#define N_EDGES 800000
#define D 128
#define NGROUPS 3125  // N_NODES / 16

typedef __attribute__((ext_vector_type(8))) short short8;
typedef __attribute__((ext_vector_type(4))) float f32x4;

__device__ __forceinline__ float bits2f(unsigned int u) {
    union { unsigned int u; float f; } c; c.u = u; return c.f;
}
__device__ __forceinline__ unsigned short f2b(float f) {
    union { float f; unsigned int u; } c; c.f = f;
    unsigned int r = c.u + 0x7fffu + ((c.u >> 16) & 1u);
    return (unsigned short)(r >> 16);
}

// ---------------- CSR build ----------------

__global__ void k_degrank(const int* __restrict__ dst, int* __restrict__ deg,
                          int* __restrict__ rank) {
    int e = blockIdx.x * blockDim.x + threadIdx.x;
    if (e < N_EDGES) rank[e] = atomicAdd(&deg[dst[e]], 1);
}

__global__ void k_scan1(const int* __restrict__ deg, int* __restrict__ rs,
                        int* __restrict__ bsum) {
    __shared__ int s[1024];
    int tid = threadIdx.x;
    int i = blockIdx.x * 1024 + tid;
    int v = (i < N_NODES) ? deg[i] : 0;
    s[tid] = v;
    __syncthreads();
    for (int off = 1; off < 1024; off <<= 1) {
        int t = (tid >= off) ? s[tid - off] : 0;
        __syncthreads();
        s[tid] += t;
        __syncthreads();
    }
    if (i < N_NODES) rs[i] = s[tid] - v;
    if (tid == 1023) bsum[blockIdx.x] = s[1023];
}

// single-wave shfl prefix scan over block sums (nb <= 64); uniform control
__global__ void k_scan2(int* __restrict__ bsum, int nb) {
    int lane = threadIdx.x;
    int v = (lane < nb) ? bsum[lane] : 0;
    int s = v;
    #pragma unroll
    for (int off = 1; off < 64; off <<= 1) {
        int t = __shfl_up(s, off, 64);
        if (lane >= off) s += t;
    }
    if (lane < nb) bsum[lane] = s - v;  // exclusive
}

__global__ void k_scan3(int* __restrict__ rs, const int* __restrict__ bsum) {
    int i = blockIdx.x * blockDim.x + threadIdx.x;
    if (i < N_NODES) rs[i] += bsum[i >> 10];
    if (i == 0) rs[N_NODES] = N_EDGES;
}

__global__ void k_fill2(const int* __restrict__ src, const int* __restrict__ dst,
                        const int* __restrict__ rs, const int* __restrict__ rank,
                        int* __restrict__ col) {
    int e = blockIdx.x * blockDim.x + threadIdx.x;
    if (e < N_EDGES) col[rs[dst[e]] + rank[e]] = src[e];
}

// ------- fused setup: f32->bf16 cast | weight pack | pad-row zeroing -------
// blocks [0,6250): cast x -> f0 (float4 -> ushort4 each thread)
// blocks [6250,6298): pack weights into MFMA B-frag order
//   Bp[layer][kstep][cf][lane][i] = W[kstep*32+8*(lane>>4)+i][cf*16+(lane&15)]
//   (kstep<4 -> w_nbr, else w_root with k offset -128)
// block 6298: zero the pad row (index N_NODES) of f0/f1/f2

__global__ void k_setup(const float* __restrict__ x,
                        const float* __restrict__ wn0, const float* __restrict__ wr0,
                        const float* __restrict__ wn1, const float* __restrict__ wr1,
                        const float* __restrict__ wn2, const float* __restrict__ wr2,
                        unsigned short* __restrict__ f0,
                        unsigned short* __restrict__ f1,
                        unsigned short* __restrict__ f2,
                        unsigned short* __restrict__ Bp) {
    int b = blockIdx.x;
    if (b < 6250) {
        int i = b * 256 + threadIdx.x;  // one float4 each, 1.6M total
        float4 v = reinterpret_cast<const float4*>(x)[i];
        ushort4 o;
        o.x = f2b(v.x); o.y = f2b(v.y); o.z = f2b(v.z); o.w = f2b(v.w);
        reinterpret_cast<ushort4*>(f0)[i] = o;
    } else if (b < 6298) {
        int t = (b - 6250) * 256 + threadIdx.x;
        if (t >= 3 * 8 * 8 * 64) return;
        int layer = t >> 12;
        int rem = t & 4095;
        int kstep = rem >> 9;
        int cf = (rem >> 6) & 7;
        int lane = t & 63;
        const float* wns[3] = {wn0, wn1, wn2};
        const float* wrs[3] = {wr0, wr1, wr2};
        int kb = kstep * 32 + (lane >> 4) * 8;
        int colv = cf * 16 + (lane & 15);
        const float* W = (kstep < 4) ? wns[layer] : wrs[layer];
        int koff = (kstep < 4) ? kb : kb - 128;
        unsigned short* dstp = Bp + (((layer * 64 + kstep * 8 + cf) * 64 + lane) << 3);
        #pragma unroll
        for (int i = 0; i < 8; ++i) dstp[i] = f2b(W[(koff + i) * D + colv]);
    } else {
        int t = threadIdx.x;
        if (t < D) {
            f0[(size_t)N_NODES * D + t] = 0;
            f1[(size_t)N_NODES * D + t] = 0;
            f2[(size_t)N_NODES * D + t] = 0;
        }
    }
}

// ---------------- mean aggregation: one node per wave ----------------
// Coalesced preload of up to 64 col indices; out-of-range slots point at the
// zeroed pad row (N_NODES) so the batch loop is wave-UNIFORM (all shfls safe,
// no divergent remainder, 16 row-loads in flight). Summation order per
// accumulator matches the round-6 kernel bit-for-bit.

#define ACCUM(v)                                                      \
    acc0 += bits2f((v).x << 16); acc1 += bits2f((v).x & 0xffff0000u); \
    acc2 += bits2f((v).y << 16); acc3 += bits2f((v).y & 0xffff0000u); \
    acc4 += bits2f((v).z << 16); acc5 += bits2f((v).z & 0xffff0000u); \
    acc6 += bits2f((v).w << 16); acc7 += bits2f((v).w & 0xffff0000u);

__global__ __launch_bounds__(256) void k_agg2(const unsigned short* __restrict__ h,
                                              const int* __restrict__ rs,
                                              const int* __restrict__ col,
                                              unsigned short* __restrict__ mean) {
    const int lane = threadIdx.x & 63;
    const int node = blockIdx.x * 4 + (threadIdx.x >> 6);
    if (node >= N_NODES) return;
    const int j0 = rs[node], j1 = rs[node + 1];
    const int deg = j1 - j0;
    const int q = lane >> 4;      // neighbor slot
    const int d8 = (lane & 15) * 8;

    // one coalesced index load; invalid lanes -> pad row (reads zeros)
    int myc = (j0 + lane < j1) ? col[j0 + lane] : N_NODES;
    const int nfull = deg < 64 ? deg : 64;
    const int nb = (nfull + 15) >> 4;   // wave-uniform batch count

    float acc0 = 0.f, acc1 = 0.f, acc2 = 0.f, acc3 = 0.f;
    float acc4 = 0.f, acc5 = 0.f, acc6 = 0.f, acc7 = 0.f;

    for (int i = 0; i < nb; ++i) {      // uniform trips: shfl always safe
        int t = (i << 4) + q;
        int c0 = __shfl(myc, t, 64);
        int c1 = __shfl(myc, t + 4, 64);
        int c2 = __shfl(myc, t + 8, 64);
        int c3 = __shfl(myc, t + 12, 64);
        uint4 v0 = *(const uint4*)(h + (size_t)c0 * D + d8);
        uint4 v1 = *(const uint4*)(h + (size_t)c1 * D + d8);
        uint4 v2 = *(const uint4*)(h + (size_t)c2 * D + d8);
        uint4 v3 = *(const uint4*)(h + (size_t)c3 * D + d8);
        ACCUM(v0); ACCUM(v1); ACCUM(v2); ACCUM(v3);
    }
    for (int j = j0 + 64 + q; j < j1; j += 4) {  // deg>64 (~never); no shfl
        int c = col[j];
        uint4 v = *(const uint4*)(h + (size_t)c * D + d8);
        ACCUM(v);
    }

    acc0 += __shfl_xor(acc0, 16, 64); acc0 += __shfl_xor(acc0, 32, 64);
    acc1 += __shfl_xor(acc1, 16, 64); acc1 += __shfl_xor(acc1, 32, 64);
    acc2 += __shfl_xor(acc2, 16, 64); acc2 += __shfl_xor(acc2, 32, 64);
    acc3 += __shfl_xor(acc3, 16, 64); acc3 += __shfl_xor(acc3, 32, 64);
    acc4 += __shfl_xor(acc4, 16, 64); acc4 += __shfl_xor(acc4, 32, 64);
    acc5 += __shfl_xor(acc5, 16, 64); acc5 += __shfl_xor(acc5, 32, 64);
    acc6 += __shfl_xor(acc6, 16, 64); acc6 += __shfl_xor(acc6, 32, 64);
    acc7 += __shfl_xor(acc7, 16, 64); acc7 += __shfl_xor(acc7, 32, 64);

    if (lane < 16) {
        float s = 1.0f / (float)(deg > 0 ? deg : 1);
        uint4 o;
        o.x = (unsigned int)f2b(acc0 * s) | ((unsigned int)f2b(acc1 * s) << 16);
        o.y = (unsigned int)f2b(acc2 * s) | ((unsigned int)f2b(acc3 * s) << 16);
        o.z = (unsigned int)f2b(acc4 * s) | ((unsigned int)f2b(acc5 * s) << 16);
        o.w = (unsigned int)f2b(acc6 * s) | ((unsigned int)f2b(acc7 * s) << 16);
        *reinterpret_cast<uint4*>(mean + (size_t)node * D + d8) = o;
    }
}

// ---------------- MFMA GEMM: out = [mean|h] @ [Wn;Wr] + b (+relu / +cls) --
// One wave per 16-row group; full N=128 (8 col-frags); K=256 in 8 steps.

template <int ACT, int CLS>
__global__ __launch_bounds__(256) void k_gemm(
    const unsigned short* __restrict__ Amean, const unsigned short* __restrict__ Ah,
    const unsigned short* __restrict__ Bp, const float* __restrict__ bias,
    unsigned short* __restrict__ outh, const float* __restrict__ wc,
    const float* __restrict__ bc, float* __restrict__ outf) {
    int lane = threadIdx.x & 63;
    int group = blockIdx.x * 4 + (threadIdx.x >> 6);
    if (group >= NGROUPS) return;
    int row0 = group * 16;
    int arow = row0 + (lane & 15);
    int klane = (lane >> 4) * 8;

    f32x4 acc[8];
    #pragma unroll
    for (int i = 0; i < 8; ++i) acc[i] = (f32x4)0.0f;

    const short8* bpv = reinterpret_cast<const short8*>(Bp);
    #pragma unroll
    for (int kstep = 0; kstep < 8; ++kstep) {
        const unsigned short* Asrc = (kstep < 4) ? Amean : Ah;
        int kk = (kstep & 3) * 32 + klane;
        short8 a = *reinterpret_cast<const short8*>(Asrc + (size_t)arow * D + kk);
        #pragma unroll
        for (int cf = 0; cf < 8; ++cf) {
            short8 b = bpv[(kstep * 8 + cf) * 64 + lane];
            acc[cf] = __builtin_amdgcn_mfma_f32_16x16x32_bf16(a, b, acc[cf], 0, 0, 0);
        }
    }

    int rbase = row0 + (lane >> 4) * 4;
    if (CLS) {
        float p0 = 0.f, p1 = 0.f, p2 = 0.f, p3 = 0.f;
        #pragma unroll
        for (int cf = 0; cf < 8; ++cf) {
            int bcol = cf * 16 + (lane & 15);
            float bv = bias[bcol];
            float wcv = wc[bcol];
            p0 += (acc[cf][0] + bv) * wcv;
            p1 += (acc[cf][1] + bv) * wcv;
            p2 += (acc[cf][2] + bv) * wcv;
            p3 += (acc[cf][3] + bv) * wcv;
        }
        #pragma unroll
        for (int m = 1; m < 16; m <<= 1) {
            p0 += __shfl_xor(p0, m, 64);
            p1 += __shfl_xor(p1, m, 64);
            p2 += __shfl_xor(p2, m, 64);
            p3 += __shfl_xor(p3, m, 64);
        }
        if ((lane & 15) == 0) {
            float bcv = bc[0];
            outf[rbase + 0] = p0 + bcv;
            outf[rbase + 1] = p1 + bcv;
            outf[rbase + 2] = p2 + bcv;
            outf[rbase + 3] = p3 + bcv;
        }
    } else {
        #pragma unroll
        for (int cf = 0; cf < 8; ++cf) {
            int bcol = cf * 16 + (lane & 15);
            float bv = bias[bcol];
            #pragma unroll
            for (int i = 0; i < 4; ++i) {
                float v = acc[cf][i] + bv;
                if (ACT) v = fmaxf(v, 0.f);
                outh[(size_t)(rbase + i) * D + bcol] = f2b(v);
            }
        }
    }
}

// ---------------- launch ----------------

extern "C" void kernel_launch(void* const* d_in, const int* in_sizes, int n_in,
                              void* d_out, int out_size, void* d_ws,
                              size_t ws_size, hipStream_t stream) {
    const float* x = (const float*)d_in[0];
    const int* ei = (const int*)d_in[1];
    const int* src = ei;
    const int* dst = ei + N_EDGES;
    const float* wn[3] = {(const float*)d_in[2], (const float*)d_in[5],
                          (const float*)d_in[8]};
    const float* wr[3] = {(const float*)d_in[3], (const float*)d_in[6],
                          (const float*)d_in[9]};
    const float* bs[3] = {(const float*)d_in[4], (const float*)d_in[7],
                          (const float*)d_in[10]};
    const float* wc = (const float*)d_in[11];
    const float* bc = (const float*)d_in[12];
    float* out = (float*)d_out;

    char* ws = (char*)d_ws;
    size_t off = 0;
    auto alloc = [&](size_t bytes) -> void* {
        void* p = (void*)(ws + off);
        off += (bytes + 255) & ~(size_t)255;
        return p;
    };
    // ~45.5 MB total. Three feature buffers (each N_NODES+1 rows; the extra
    // row N_NODES is kept zero as the gather's safe pad target), rotated as
    // in/mean/out; each write target is dead at write time.
    const size_t frows = (size_t)(N_NODES + 1) * D;
    int* deg = (int*)alloc(N_NODES * 4);
    int* rs = (int*)alloc((N_NODES + 1) * 4);
    int* rank = (int*)alloc(N_EDGES * 4);
    int* bsum = (int*)alloc(64 * 4);
    int* col = (int*)alloc(N_EDGES * 4);
    unsigned short* f0 = (unsigned short*)alloc(frows * 2);
    unsigned short* f1 = (unsigned short*)alloc(frows * 2);
    unsigned short* f2 = (unsigned short*)alloc(frows * 2);
    unsigned short* Bp = (unsigned short*)alloc(3 * 256 * 128 * 2);

    hipMemsetAsync(deg, 0, N_NODES * 4, stream);

    int nb = (N_NODES + 1023) / 1024;
    k_degrank<<<(N_EDGES + 255) / 256, 256, 0, stream>>>(dst, deg, rank);
    k_scan1<<<nb, 1024, 0, stream>>>(deg, rs, bsum);
    k_scan2<<<1, 64, 0, stream>>>(bsum, nb);
    k_scan3<<<(N_NODES + 255) / 256, 256, 0, stream>>>(rs, bsum);
    k_fill2<<<(N_EDGES + 255) / 256, 256, 0, stream>>>(src, dst, rs, rank, col);

    k_setup<<<6299, 256, 0, stream>>>(x, wn[0], wr[0], wn[1], wr[1], wn[2],
                                      wr[2], f0, f1, f2, Bp);

    const int agg_grid = (N_NODES + 3) / 4;
    const int gemm_grid = (NGROUPS + 3) / 4;
    unsigned short* Bp0 = Bp;
    unsigned short* Bp1 = Bp + 256 * 128;
    unsigned short* Bp2 = Bp + 2 * 256 * 128;

    // layer 0: in=f0, mean=f1, out=f2 (relu)
    k_agg2<<<agg_grid, 256, 0, stream>>>(f0, rs, col, f1);
    k_gemm<1, 0><<<gemm_grid, 256, 0, stream>>>(f1, f0, Bp0, bs[0], f2,
                                                nullptr, nullptr, nullptr);
    // layer 1: in=f2, mean=f0, out=f1 (relu)
    k_agg2<<<agg_grid, 256, 0, stream>>>(f2, rs, col, f0);
    k_gemm<1, 0><<<gemm_grid, 256, 0, stream>>>(f0, f2, Bp1, bs[1], f1,
                                                nullptr, nullptr, nullptr);
    // layer 2 + classifier: in=f1, mean=f2, out=d_out (f32)
    k_agg2<<<agg_grid, 256, 0, stream>>>(f1, rs, col, f2);
    k_gemm<0, 1><<<gemm_grid, 256, 0, stream>>>(f2, f1, Bp2, bs[2], nullptr,
                                                wc, bc, out);
}

// Round 9
// 180.875 us; speedup vs baseline: 1.2129x; 1.0724x over previous
//
#include <hip/hip_runtime.h>

#define N_NODES 50000
#define N_EDGES 800000
#define D 128
#define NGROUPS 3125  // N_NODES / 16

typedef __attribute__((ext_vector_type(8))) short short8;
typedef __attribute__((ext_vector_type(4))) float f32x4;

__device__ __forceinline__ float bits2f(unsigned int u) {
    union { unsigned int u; float f; } c; c.u = u; return c.f;
}
__device__ __forceinline__ unsigned short f2b(float f) {
    union { float f; unsigned int u; } c; c.f = f;
    unsigned int r = c.u + 0x7fffu + ((c.u >> 16) & 1u);
    return (unsigned short)(r >> 16);
}
__device__ __forceinline__ float b2f(unsigned short b) {
    return bits2f(((unsigned int)b) << 16);
}

// ---------------- CSR build ----------------

__global__ void k_degrank(const int* __restrict__ dst, int* __restrict__ deg,
                          int* __restrict__ rank) {
    int e = blockIdx.x * blockDim.x + threadIdx.x;
    if (e < N_EDGES) rank[e] = atomicAdd(&deg[dst[e]], 1);
}

__global__ void k_scan1(const int* __restrict__ deg, int* __restrict__ rs,
                        int* __restrict__ bsum) {
    __shared__ int s[1024];
    int tid = threadIdx.x;
    int i = blockIdx.x * 1024 + tid;
    int v = (i < N_NODES) ? deg[i] : 0;
    s[tid] = v;
    __syncthreads();
    for (int off = 1; off < 1024; off <<= 1) {
        int t = (tid >= off) ? s[tid - off] : 0;
        __syncthreads();
        s[tid] += t;
        __syncthreads();
    }
    if (i < N_NODES) rs[i] = s[tid] - v;
    if (tid == 1023) bsum[blockIdx.x] = s[1023];
}

// fused scan2+scan3: wave 0 of every block redoes the (cheap) 49-element
// exclusive scan of block sums, then all threads apply the offset.
__global__ void k_scan23(int* __restrict__ rs, const int* __restrict__ bsum,
                         int nb) {
    __shared__ int bp[64];
    if (threadIdx.x < 64) {
        int lane = threadIdx.x;  // full wave 0: shfl safe
        int v = (lane < nb) ? bsum[lane] : 0;
        int s = v;
        #pragma unroll
        for (int off = 1; off < 64; off <<= 1) {
            int t = __shfl_up(s, off, 64);
            if (lane >= off) s += t;
        }
        bp[lane] = s - v;  // exclusive
    }
    __syncthreads();
    int i = blockIdx.x * blockDim.x + threadIdx.x;
    if (i < N_NODES) rs[i] += bp[i >> 10];
    if (i == 0) rs[N_NODES] = N_EDGES;
}

__global__ void k_fill2(const int* __restrict__ src, const int* __restrict__ dst,
                        const int* __restrict__ rs, const int* __restrict__ rank,
                        int* __restrict__ col) {
    int e = blockIdx.x * blockDim.x + threadIdx.x;
    if (e < N_EDGES) col[rs[dst[e]] + rank[e]] = src[e];
}

// ------- fused setup: cast | pack W0,W1 | pad zero | u,v,c for layer 2 ----
// u = Wn2 @ wc, v = Wr2 @ wc, c = b2.wc + bc  (layer-2+classifier collapse)

__global__ void k_setup(const float* __restrict__ x,
                        const float* __restrict__ wn0, const float* __restrict__ wr0,
                        const float* __restrict__ wn1, const float* __restrict__ wr1,
                        const float* __restrict__ wn2, const float* __restrict__ wr2,
                        const float* __restrict__ b2, const float* __restrict__ wc,
                        const float* __restrict__ bc,
                        unsigned short* __restrict__ f0,
                        unsigned short* __restrict__ f1,
                        unsigned short* __restrict__ f2,
                        unsigned short* __restrict__ Bp,
                        float* __restrict__ uvc) {
    int b = blockIdx.x;
    if (b < 6250) {
        int i = b * 256 + threadIdx.x;  // one float4 each, 1.6M total
        float4 v = reinterpret_cast<const float4*>(x)[i];
        ushort4 o;
        o.x = f2b(v.x); o.y = f2b(v.y); o.z = f2b(v.z); o.w = f2b(v.w);
        reinterpret_cast<ushort4*>(f0)[i] = o;
    } else if (b < 6282) {  // pack layers 0,1
        int t = (b - 6250) * 256 + threadIdx.x;
        if (t >= 2 * 8 * 8 * 64) return;
        int layer = t >> 12;
        int rem = t & 4095;
        int kstep = rem >> 9;
        int cf = (rem >> 6) & 7;
        int lane = t & 63;
        const float* W = (kstep < 4) ? (layer ? wn1 : wn0) : (layer ? wr1 : wr0);
        int kb = kstep * 32 + (lane >> 4) * 8;
        int colv = cf * 16 + (lane & 15);
        int koff = (kstep < 4) ? kb : kb - 128;
        unsigned short* dstp = Bp + (((layer * 64 + kstep * 8 + cf) * 64 + lane) << 3);
        #pragma unroll
        for (int i = 0; i < 8; ++i) dstp[i] = f2b(W[(koff + i) * D + colv]);
    } else if (b == 6282) {
        int t = threadIdx.x;
        if (t < D) {
            f0[(size_t)N_NODES * D + t] = 0;
            f1[(size_t)N_NODES * D + t] = 0;
            f2[(size_t)N_NODES * D + t] = 0;
        }
    } else {
        int t = threadIdx.x;
        if (t < 128) {
            float su = 0.f;
            for (int m = 0; m < 128; ++m) su += wn2[t * D + m] * wc[m];
            uvc[t] = su;
        } else {
            int k = t - 128;
            float sv = 0.f;
            for (int m = 0; m < 128; ++m) sv += wr2[k * D + m] * wc[m];
            uvc[128 + k] = sv;
        }
        if (t == 0) {
            float sc = 0.f;
            for (int m = 0; m < 128; ++m) sc += b2[m] * wc[m];
            uvc[256] = sc + bc[0];
        }
    }
}

// ---------------- mean aggregation: one node per wave (validated r8) ------

#define ACCUM(v)                                                      \
    acc0 += bits2f((v).x << 16); acc1 += bits2f((v).x & 0xffff0000u); \
    acc2 += bits2f((v).y << 16); acc3 += bits2f((v).y & 0xffff0000u); \
    acc4 += bits2f((v).z << 16); acc5 += bits2f((v).z & 0xffff0000u); \
    acc6 += bits2f((v).w << 16); acc7 += bits2f((v).w & 0xffff0000u);

__global__ __launch_bounds__(256) void k_agg2(const unsigned short* __restrict__ h,
                                              const int* __restrict__ rs,
                                              const int* __restrict__ col,
                                              unsigned short* __restrict__ mean) {
    const int lane = threadIdx.x & 63;
    const int node = blockIdx.x * 4 + (threadIdx.x >> 6);
    if (node >= N_NODES) return;
    const int j0 = rs[node], j1 = rs[node + 1];
    const int deg = j1 - j0;
    const int q = lane >> 4;
    const int d8 = (lane & 15) * 8;

    int myc = (j0 + lane < j1) ? col[j0 + lane] : N_NODES;  // pad row: zeros
    const int nfull = deg < 64 ? deg : 64;
    const int nb = (nfull + 15) >> 4;   // wave-uniform batch count

    float acc0 = 0.f, acc1 = 0.f, acc2 = 0.f, acc3 = 0.f;
    float acc4 = 0.f, acc5 = 0.f, acc6 = 0.f, acc7 = 0.f;

    for (int i = 0; i < nb; ++i) {      // uniform trips: shfl always safe
        int t = (i << 4) + q;
        int c0 = __shfl(myc, t, 64);
        int c1 = __shfl(myc, t + 4, 64);
        int c2 = __shfl(myc, t + 8, 64);
        int c3 = __shfl(myc, t + 12, 64);
        uint4 v0 = *(const uint4*)(h + (size_t)c0 * D + d8);
        uint4 v1 = *(const uint4*)(h + (size_t)c1 * D + d8);
        uint4 v2 = *(const uint4*)(h + (size_t)c2 * D + d8);
        uint4 v3 = *(const uint4*)(h + (size_t)c3 * D + d8);
        ACCUM(v0); ACCUM(v1); ACCUM(v2); ACCUM(v3);
    }
    for (int j = j0 + 64 + q; j < j1; j += 4) {  // deg>64 (~never); no shfl
        int c = col[j];
        uint4 v = *(const uint4*)(h + (size_t)c * D + d8);
        ACCUM(v);
    }

    acc0 += __shfl_xor(acc0, 16, 64); acc0 += __shfl_xor(acc0, 32, 64);
    acc1 += __shfl_xor(acc1, 16, 64); acc1 += __shfl_xor(acc1, 32, 64);
    acc2 += __shfl_xor(acc2, 16, 64); acc2 += __shfl_xor(acc2, 32, 64);
    acc3 += __shfl_xor(acc3, 16, 64); acc3 += __shfl_xor(acc3, 32, 64);
    acc4 += __shfl_xor(acc4, 16, 64); acc4 += __shfl_xor(acc4, 32, 64);
    acc5 += __shfl_xor(acc5, 16, 64); acc5 += __shfl_xor(acc5, 32, 64);
    acc6 += __shfl_xor(acc6, 16, 64); acc6 += __shfl_xor(acc6, 32, 64);
    acc7 += __shfl_xor(acc7, 16, 64); acc7 += __shfl_xor(acc7, 32, 64);

    if (lane < 16) {
        float s = 1.0f / (float)(deg > 0 ? deg : 1);
        uint4 o;
        o.x = (unsigned int)f2b(acc0 * s) | ((unsigned int)f2b(acc1 * s) << 16);
        o.y = (unsigned int)f2b(acc2 * s) | ((unsigned int)f2b(acc3 * s) << 16);
        o.z = (unsigned int)f2b(acc4 * s) | ((unsigned int)f2b(acc5 * s) << 16);
        o.w = (unsigned int)f2b(acc6 * s) | ((unsigned int)f2b(acc7 * s) << 16);
        *reinterpret_cast<uint4*>(mean + (size_t)node * D + d8) = o;
    }
}

// ---------------- MFMA GEMM (relu): 2 row-groups per wave ----------------
// B-frags loaded once per kstep, reused for both groups (halves B traffic).

__global__ __launch_bounds__(256) void k_gemm(
    const unsigned short* __restrict__ Amean, const unsigned short* __restrict__ Ah,
    const unsigned short* __restrict__ Bp, const float* __restrict__ bias,
    unsigned short* __restrict__ outh) {
    int lane = threadIdx.x & 63;
    int w = blockIdx.x * 4 + (threadIdx.x >> 6);
    int g0 = w * 2;
    if (g0 >= NGROUPS) return;
    int g1ok = (g0 + 1 < NGROUPS);
    int hl = lane & 15;
    int klane = (lane >> 4) * 8;
    int arow0 = g0 * 16 + hl;
    int arow1 = g0 * 16 + 16 + hl;
    if (arow1 > N_NODES) arow1 = N_NODES;  // pad row (zeros) when g1 invalid

    f32x4 acc0[8], acc1[8];
    #pragma unroll
    for (int i = 0; i < 8; ++i) { acc0[i] = (f32x4)0.0f; acc1[i] = (f32x4)0.0f; }

    const short8* bpv = reinterpret_cast<const short8*>(Bp);
    #pragma unroll
    for (int kstep = 0; kstep < 8; ++kstep) {
        const unsigned short* Asrc = (kstep < 4) ? Amean : Ah;
        int kk = (kstep & 3) * 32 + klane;
        short8 a0 = *reinterpret_cast<const short8*>(Asrc + (size_t)arow0 * D + kk);
        short8 a1 = *reinterpret_cast<const short8*>(Asrc + (size_t)arow1 * D + kk);
        #pragma unroll
        for (int cf = 0; cf < 8; ++cf) {
            short8 b = bpv[(kstep * 8 + cf) * 64 + lane];
            acc0[cf] = __builtin_amdgcn_mfma_f32_16x16x32_bf16(a0, b, acc0[cf], 0, 0, 0);
            acc1[cf] = __builtin_amdgcn_mfma_f32_16x16x32_bf16(a1, b, acc1[cf], 0, 0, 0);
        }
    }

    int rbase0 = g0 * 16 + (lane >> 4) * 4;
    #pragma unroll
    for (int cf = 0; cf < 8; ++cf) {
        int bcol = cf * 16 + hl;
        float bv = bias[bcol];
        #pragma unroll
        for (int i = 0; i < 4; ++i) {
            float v = fmaxf(acc0[cf][i] + bv, 0.f);
            outh[(size_t)(rbase0 + i) * D + bcol] = f2b(v);
            if (g1ok) {
                float v1 = fmaxf(acc1[cf][i] + bv, 0.f);
                outh[(size_t)(rbase0 + 16 + i) * D + bcol] = f2b(v1);
            }
        }
    }
}

// ---------------- layer-2 collapse: s = h2.u, t = h2.v -------------------
// 4 nodes per wave (16 lanes each, 8 dims per lane), shfl-reduce in group.

__global__ __launch_bounds__(256) void k_dot(const unsigned short* __restrict__ h2,
                                             const float* __restrict__ uvc,
                                             float* __restrict__ s,
                                             float* __restrict__ t) {
    const int lane = threadIdx.x & 63;
    const int node = blockIdx.x * 16 + (threadIdx.x >> 6) * 4 + (lane >> 4);
    const int hl = lane & 15;
    const int d8 = hl * 8;
    if (node >= N_NODES) return;
    uint4 hv = *(const uint4*)(h2 + (size_t)node * D + d8);
    float4 ua = *(const float4*)(uvc + d8);
    float4 ub = *(const float4*)(uvc + d8 + 4);
    float4 va = *(const float4*)(uvc + 128 + d8);
    float4 vb = *(const float4*)(uvc + 128 + d8 + 4);
    float h0 = bits2f(hv.x << 16), h1 = bits2f(hv.x & 0xffff0000u);
    float h2v = bits2f(hv.y << 16), h3 = bits2f(hv.y & 0xffff0000u);
    float h4 = bits2f(hv.z << 16), h5 = bits2f(hv.z & 0xffff0000u);
    float h6 = bits2f(hv.w << 16), h7 = bits2f(hv.w & 0xffff0000u);
    float ps = h0 * ua.x + h1 * ua.y + h2v * ua.z + h3 * ua.w +
               h4 * ub.x + h5 * ub.y + h6 * ub.z + h7 * ub.w;
    float pt = h0 * va.x + h1 * va.y + h2v * va.z + h3 * va.w +
               h4 * vb.x + h5 * vb.y + h6 * vb.z + h7 * vb.w;
    #pragma unroll
    for (int m = 1; m < 16; m <<= 1) {
        ps += __shfl_xor(ps, m, 64);
        pt += __shfl_xor(pt, m, 64);
    }
    if (hl == 0) { s[node] = ps; t[node] = pt; }
}

// scalar mean-gather + epilogue: out[i] = mean_j s[col] + t[i] + c
__global__ __launch_bounds__(256) void k_sagg(const float* __restrict__ s,
                                              const float* __restrict__ t,
                                              const float* __restrict__ uvc,
                                              const int* __restrict__ rs,
                                              const int* __restrict__ col,
                                              float* __restrict__ out) {
    int i = blockIdx.x * blockDim.x + threadIdx.x;
    if (i >= N_NODES) return;
    int j0 = rs[i], j1 = rs[i + 1];
    float sm = 0.f;
    for (int j = j0; j < j1; ++j) sm += s[col[j]];
    int deg = j1 - j0;
    out[i] = sm / (float)(deg > 0 ? deg : 1) + t[i] + uvc[256];
}

// ---------------- launch ----------------

extern "C" void kernel_launch(void* const* d_in, const int* in_sizes, int n_in,
                              void* d_out, int out_size, void* d_ws,
                              size_t ws_size, hipStream_t stream) {
    const float* x = (const float*)d_in[0];
    const int* ei = (const int*)d_in[1];
    const int* src = ei;
    const int* dst = ei + N_EDGES;
    const float* wn[3] = {(const float*)d_in[2], (const float*)d_in[5],
                          (const float*)d_in[8]};
    const float* wr[3] = {(const float*)d_in[3], (const float*)d_in[6],
                          (const float*)d_in[9]};
    const float* bs[3] = {(const float*)d_in[4], (const float*)d_in[7],
                          (const float*)d_in[10]};
    const float* wc = (const float*)d_in[11];
    const float* bc = (const float*)d_in[12];
    float* out = (float*)d_out;

    char* ws = (char*)d_ws;
    size_t off = 0;
    auto alloc = [&](size_t bytes) -> void* {
        void* p = (void*)(ws + off);
        off += (bytes + 255) & ~(size_t)255;
        return p;
    };
    const size_t frows = (size_t)(N_NODES + 1) * D;
    int* deg = (int*)alloc(N_NODES * 4);
    int* rs = (int*)alloc((N_NODES + 1) * 4);
    int* rank = (int*)alloc(N_EDGES * 4);
    int* bsum = (int*)alloc(64 * 4);
    int* col = (int*)alloc(N_EDGES * 4);
    unsigned short* f0 = (unsigned short*)alloc(frows * 2);
    unsigned short* f1 = (unsigned short*)alloc(frows * 2);
    unsigned short* f2 = (unsigned short*)alloc(frows * 2);
    unsigned short* Bp = (unsigned short*)alloc(2 * 256 * 128 * 2);
    float* uvc = (float*)alloc(260 * 4);
    float* sbuf = (float*)alloc(N_NODES * 4);
    float* tbuf = (float*)alloc(N_NODES * 4);

    hipMemsetAsync(deg, 0, N_NODES * 4, stream);

    int nb = (N_NODES + 1023) / 1024;
    k_degrank<<<(N_EDGES + 255) / 256, 256, 0, stream>>>(dst, deg, rank);
    k_scan1<<<nb, 1024, 0, stream>>>(deg, rs, bsum);
    k_scan23<<<(N_NODES + 255) / 256, 256, 0, stream>>>(rs, bsum, nb);
    k_fill2<<<(N_EDGES + 255) / 256, 256, 0, stream>>>(src, dst, rs, rank, col);

    k_setup<<<6284, 256, 0, stream>>>(x, wn[0], wr[0], wn[1], wr[1], wn[2],
                                      wr[2], bs[2], wc, bc, f0, f1, f2, Bp, uvc);

    const int agg_grid = (N_NODES + 3) / 4;
    const int gemm_grid = ((NGROUPS + 1) / 2 + 3) / 4;
    unsigned short* Bp0 = Bp;
    unsigned short* Bp1 = Bp + 256 * 128;

    // layer 0: in=f0, mean=f1, out=f2 (relu)
    k_agg2<<<agg_grid, 256, 0, stream>>>(f0, rs, col, f1);
    k_gemm<<<gemm_grid, 256, 0, stream>>>(f1, f0, Bp0, bs[0], f2);
    // layer 1: in=f2, mean=f0, out=f1 (relu)
    k_agg2<<<agg_grid, 256, 0, stream>>>(f2, rs, col, f0);
    k_gemm<<<gemm_grid, 256, 0, stream>>>(f0, f2, Bp1, bs[1], f1);
    // layer 2 + classifier, collapsed: s=f1.u, t=f1.v; out = mean(s)+t+c
    k_dot<<<(N_NODES + 15) / 16, 256, 0, stream>>>(f1, uvc, sbuf, tbuf);
    k_sagg<<<(N_NODES + 255) / 256, 256, 0, stream>>>(sbuf, tbuf, uvc, rs, col,
                                                      out);
}

// Round 10
// 163.286 us; speedup vs baseline: 1.3436x; 1.1077x over previous
//
#include <hip/hip_runtime.h>

#define N_NODES 50000
#define N_EDGES 800000
#define D 128
#define NGROUPS 3125  // N_NODES / 16

typedef __attribute__((ext_vector_type(8))) short short8;
typedef __attribute__((ext_vector_type(4))) float f32x4;

__device__ __forceinline__ float bits2f(unsigned int u) {
    union { unsigned int u; float f; } c; c.u = u; return c.f;
}
__device__ __forceinline__ unsigned short f2b(float f) {
    union { float f; unsigned int u; } c; c.f = f;
    unsigned int r = c.u + 0x7fffu + ((c.u >> 16) & 1u);
    return (unsigned short)(r >> 16);
}

// ---- mega-kernel 1: degrank | cast | pack W0,W1 | pad zero | u,v,c -------
// blocks [0,3125):    rank[e] = atomicAdd(&deg[dst[e]],1)   (800k = 3125*256)
// blocks [3125,9375): cast x -> f0 (one float4/thread, 1.6M = 6250*256)
// blocks [9375,9407): pack W0,W1 into MFMA B-frag order (8192 = 32*256)
// block 9407:         zero pad row N_NODES of f0/f1/f2
// block 9408:         u = Wn2@wc, v = Wr2@wc, c = b2.wc + bc

__global__ void k_big(const int* __restrict__ dst, int* __restrict__ deg,
                      int* __restrict__ rank, const float* __restrict__ x,
                      const float* __restrict__ wn0, const float* __restrict__ wr0,
                      const float* __restrict__ wn1, const float* __restrict__ wr1,
                      const float* __restrict__ wn2, const float* __restrict__ wr2,
                      const float* __restrict__ b2, const float* __restrict__ wc,
                      const float* __restrict__ bc,
                      unsigned short* __restrict__ f0,
                      unsigned short* __restrict__ f1,
                      unsigned short* __restrict__ f2,
                      unsigned short* __restrict__ Bp,
                      float* __restrict__ uvc) {
    int b = blockIdx.x;
    if (b < 3125) {
        int e = b * 256 + threadIdx.x;
        rank[e] = atomicAdd(&deg[dst[e]], 1);
    } else if (b < 9375) {
        int i = (b - 3125) * 256 + threadIdx.x;
        float4 v = reinterpret_cast<const float4*>(x)[i];
        ushort4 o;
        o.x = f2b(v.x); o.y = f2b(v.y); o.z = f2b(v.z); o.w = f2b(v.w);
        reinterpret_cast<ushort4*>(f0)[i] = o;
    } else if (b < 9407) {
        int t = (b - 9375) * 256 + threadIdx.x;  // < 8192 = 2*8*8*64
        int layer = t >> 12;
        int rem = t & 4095;
        int kstep = rem >> 9;
        int cf = (rem >> 6) & 7;
        int lane = t & 63;
        const float* W = (kstep < 4) ? (layer ? wn1 : wn0) : (layer ? wr1 : wr0);
        int kb = kstep * 32 + (lane >> 4) * 8;
        int colv = cf * 16 + (lane & 15);
        int koff = (kstep < 4) ? kb : kb - 128;
        unsigned short* dstp = Bp + (((layer * 64 + kstep * 8 + cf) * 64 + lane) << 3);
        #pragma unroll
        for (int i = 0; i < 8; ++i) dstp[i] = f2b(W[(koff + i) * D + colv]);
    } else if (b == 9407) {
        int t = threadIdx.x;
        if (t < D) {
            f0[(size_t)N_NODES * D + t] = 0;
            f1[(size_t)N_NODES * D + t] = 0;
            f2[(size_t)N_NODES * D + t] = 0;
        }
    } else {
        int t = threadIdx.x;
        if (t < 128) {
            float su = 0.f;
            for (int m = 0; m < 128; ++m) su += wn2[t * D + m] * wc[m];
            uvc[t] = su;
        } else {
            int k = t - 128;
            float sv = 0.f;
            for (int m = 0; m < 128; ++m) sv += wr2[k * D + m] * wc[m];
            uvc[128 + k] = sv;
        }
        if (t == 0) {
            float sc = 0.f;
            for (int m = 0; m < 128; ++m) sc += b2[m] * wc[m];
            uvc[256] = sc + bc[0];
        }
    }
}

// ---------------- CSR scan + fill (validated r9) ----------------

__global__ void k_scan1(const int* __restrict__ deg, int* __restrict__ rs,
                        int* __restrict__ bsum) {
    __shared__ int s[1024];
    int tid = threadIdx.x;
    int i = blockIdx.x * 1024 + tid;
    int v = (i < N_NODES) ? deg[i] : 0;
    s[tid] = v;
    __syncthreads();
    for (int off = 1; off < 1024; off <<= 1) {
        int t = (tid >= off) ? s[tid - off] : 0;
        __syncthreads();
        s[tid] += t;
        __syncthreads();
    }
    if (i < N_NODES) rs[i] = s[tid] - v;
    if (tid == 1023) bsum[blockIdx.x] = s[1023];
}

__global__ void k_scan23(int* __restrict__ rs, const int* __restrict__ bsum,
                         int nb) {
    __shared__ int bp[64];
    if (threadIdx.x < 64) {
        int lane = threadIdx.x;  // full wave 0: shfl safe
        int v = (lane < nb) ? bsum[lane] : 0;
        int s = v;
        #pragma unroll
        for (int off = 1; off < 64; off <<= 1) {
            int t = __shfl_up(s, off, 64);
            if (lane >= off) s += t;
        }
        bp[lane] = s - v;  // exclusive
    }
    __syncthreads();
    int i = blockIdx.x * blockDim.x + threadIdx.x;
    if (i < N_NODES) rs[i] += bp[i >> 10];
    if (i == 0) rs[N_NODES] = N_EDGES;
}

__global__ void k_fill2(const int* __restrict__ src, const int* __restrict__ dst,
                        const int* __restrict__ rs, const int* __restrict__ rank,
                        int* __restrict__ col) {
    int e = blockIdx.x * blockDim.x + threadIdx.x;
    if (e < N_EDGES) col[rs[dst[e]] + rank[e]] = src[e];
}

// ---------------- mean aggregation: one node per wave (validated r8) ------

#define ACCUM(v)                                                      \
    acc0 += bits2f((v).x << 16); acc1 += bits2f((v).x & 0xffff0000u); \
    acc2 += bits2f((v).y << 16); acc3 += bits2f((v).y & 0xffff0000u); \
    acc4 += bits2f((v).z << 16); acc5 += bits2f((v).z & 0xffff0000u); \
    acc6 += bits2f((v).w << 16); acc7 += bits2f((v).w & 0xffff0000u);

__global__ __launch_bounds__(256) void k_agg2(const unsigned short* __restrict__ h,
                                              const int* __restrict__ rs,
                                              const int* __restrict__ col,
                                              unsigned short* __restrict__ mean) {
    const int lane = threadIdx.x & 63;
    const int node = blockIdx.x * 4 + (threadIdx.x >> 6);
    if (node >= N_NODES) return;
    const int j0 = rs[node], j1 = rs[node + 1];
    const int deg = j1 - j0;
    const int q = lane >> 4;
    const int d8 = (lane & 15) * 8;

    int myc = (j0 + lane < j1) ? col[j0 + lane] : N_NODES;  // pad row: zeros
    const int nfull = deg < 64 ? deg : 64;
    const int nb = (nfull + 15) >> 4;   // wave-uniform batch count

    float acc0 = 0.f, acc1 = 0.f, acc2 = 0.f, acc3 = 0.f;
    float acc4 = 0.f, acc5 = 0.f, acc6 = 0.f, acc7 = 0.f;

    for (int i = 0; i < nb; ++i) {      // uniform trips: shfl always safe
        int t = (i << 4) + q;
        int c0 = __shfl(myc, t, 64);
        int c1 = __shfl(myc, t + 4, 64);
        int c2 = __shfl(myc, t + 8, 64);
        int c3 = __shfl(myc, t + 12, 64);
        uint4 v0 = *(const uint4*)(h + (size_t)c0 * D + d8);
        uint4 v1 = *(const uint4*)(h + (size_t)c1 * D + d8);
        uint4 v2 = *(const uint4*)(h + (size_t)c2 * D + d8);
        uint4 v3 = *(const uint4*)(h + (size_t)c3 * D + d8);
        ACCUM(v0); ACCUM(v1); ACCUM(v2); ACCUM(v3);
    }
    for (int j = j0 + 64 + q; j < j1; j += 4) {  // deg>64 (~never); no shfl
        int c = col[j];
        uint4 v = *(const uint4*)(h + (size_t)c * D + d8);
        ACCUM(v);
    }

    acc0 += __shfl_xor(acc0, 16, 64); acc0 += __shfl_xor(acc0, 32, 64);
    acc1 += __shfl_xor(acc1, 16, 64); acc1 += __shfl_xor(acc1, 32, 64);
    acc2 += __shfl_xor(acc2, 16, 64); acc2 += __shfl_xor(acc2, 32, 64);
    acc3 += __shfl_xor(acc3, 16, 64); acc3 += __shfl_xor(acc3, 32, 64);
    acc4 += __shfl_xor(acc4, 16, 64); acc4 += __shfl_xor(acc4, 32, 64);
    acc5 += __shfl_xor(acc5, 16, 64); acc5 += __shfl_xor(acc5, 32, 64);
    acc6 += __shfl_xor(acc6, 16, 64); acc6 += __shfl_xor(acc6, 32, 64);
    acc7 += __shfl_xor(acc7, 16, 64); acc7 += __shfl_xor(acc7, 32, 64);

    if (lane < 16) {
        float s = 1.0f / (float)(deg > 0 ? deg : 1);
        uint4 o;
        o.x = (unsigned int)f2b(acc0 * s) | ((unsigned int)f2b(acc1 * s) << 16);
        o.y = (unsigned int)f2b(acc2 * s) | ((unsigned int)f2b(acc3 * s) << 16);
        o.z = (unsigned int)f2b(acc4 * s) | ((unsigned int)f2b(acc5 * s) << 16);
        o.w = (unsigned int)f2b(acc6 * s) | ((unsigned int)f2b(acc7 * s) << 16);
        *reinterpret_cast<uint4*>(mean + (size_t)node * D + d8) = o;
    }
}

// ---------------- MFMA GEMM (relu, layer 0): 2 row-groups per wave --------

__global__ __launch_bounds__(256) void k_gemm(
    const unsigned short* __restrict__ Amean, const unsigned short* __restrict__ Ah,
    const unsigned short* __restrict__ Bp, const float* __restrict__ bias,
    unsigned short* __restrict__ outh) {
    int lane = threadIdx.x & 63;
    int w = blockIdx.x * 4 + (threadIdx.x >> 6);
    int g0 = w * 2;
    if (g0 >= NGROUPS) return;
    int g1ok = (g0 + 1 < NGROUPS);
    int hl = lane & 15;
    int klane = (lane >> 4) * 8;
    int arow0 = g0 * 16 + hl;
    int arow1 = g0 * 16 + 16 + hl;
    if (arow1 > N_NODES) arow1 = N_NODES;  // pad row (zeros) when g1 invalid

    f32x4 acc0[8], acc1[8];
    #pragma unroll
    for (int i = 0; i < 8; ++i) { acc0[i] = (f32x4)0.0f; acc1[i] = (f32x4)0.0f; }

    const short8* bpv = reinterpret_cast<const short8*>(Bp);
    #pragma unroll
    for (int kstep = 0; kstep < 8; ++kstep) {
        const unsigned short* Asrc = (kstep < 4) ? Amean : Ah;
        int kk = (kstep & 3) * 32 + klane;
        short8 a0 = *reinterpret_cast<const short8*>(Asrc + (size_t)arow0 * D + kk);
        short8 a1 = *reinterpret_cast<const short8*>(Asrc + (size_t)arow1 * D + kk);
        #pragma unroll
        for (int cf = 0; cf < 8; ++cf) {
            short8 b = bpv[(kstep * 8 + cf) * 64 + lane];
            acc0[cf] = __builtin_amdgcn_mfma_f32_16x16x32_bf16(a0, b, acc0[cf], 0, 0, 0);
            acc1[cf] = __builtin_amdgcn_mfma_f32_16x16x32_bf16(a1, b, acc1[cf], 0, 0, 0);
        }
    }

    int rbase0 = g0 * 16 + (lane >> 4) * 4;
    #pragma unroll
    for (int cf = 0; cf < 8; ++cf) {
        int bcol = cf * 16 + hl;
        float bv = bias[bcol];
        #pragma unroll
        for (int i = 0; i < 4; ++i) {
            float v = fmaxf(acc0[cf][i] + bv, 0.f);
            outh[(size_t)(rbase0 + i) * D + bcol] = f2b(v);
            if (g1ok) {
                float v1 = fmaxf(acc1[cf][i] + bv, 0.f);
                outh[(size_t)(rbase0 + 16 + i) * D + bcol] = f2b(v1);
            }
        }
    }
}

// ---- MFMA GEMM layer 1 + fused dot: s = relu(row).u, t = relu(row).v -----
// h2 never materialized. Reduction over hl (16 lanes) = validated CLS path.

__global__ __launch_bounds__(256) void k_gemm_dot(
    const unsigned short* __restrict__ Amean, const unsigned short* __restrict__ Ah,
    const unsigned short* __restrict__ Bp, const float* __restrict__ bias,
    const float* __restrict__ uvc, float* __restrict__ s, float* __restrict__ t) {
    int lane = threadIdx.x & 63;
    int w = blockIdx.x * 4 + (threadIdx.x >> 6);
    int g0 = w * 2;
    if (g0 >= NGROUPS) return;
    int g1ok = (g0 + 1 < NGROUPS);
    int hl = lane & 15;
    int klane = (lane >> 4) * 8;
    int arow0 = g0 * 16 + hl;
    int arow1 = g0 * 16 + 16 + hl;
    if (arow1 > N_NODES) arow1 = N_NODES;

    f32x4 acc0[8], acc1[8];
    #pragma unroll
    for (int i = 0; i < 8; ++i) { acc0[i] = (f32x4)0.0f; acc1[i] = (f32x4)0.0f; }

    const short8* bpv = reinterpret_cast<const short8*>(Bp);
    #pragma unroll
    for (int kstep = 0; kstep < 8; ++kstep) {
        const unsigned short* Asrc = (kstep < 4) ? Amean : Ah;
        int kk = (kstep & 3) * 32 + klane;
        short8 a0 = *reinterpret_cast<const short8*>(Asrc + (size_t)arow0 * D + kk);
        short8 a1 = *reinterpret_cast<const short8*>(Asrc + (size_t)arow1 * D + kk);
        #pragma unroll
        for (int cf = 0; cf < 8; ++cf) {
            short8 b = bpv[(kstep * 8 + cf) * 64 + lane];
            acc0[cf] = __builtin_amdgcn_mfma_f32_16x16x32_bf16(a0, b, acc0[cf], 0, 0, 0);
            acc1[cf] = __builtin_amdgcn_mfma_f32_16x16x32_bf16(a1, b, acc1[cf], 0, 0, 0);
        }
    }

    float ps0[4] = {0.f, 0.f, 0.f, 0.f}, pt0[4] = {0.f, 0.f, 0.f, 0.f};
    float ps1[4] = {0.f, 0.f, 0.f, 0.f}, pt1[4] = {0.f, 0.f, 0.f, 0.f};
    #pragma unroll
    for (int cf = 0; cf < 8; ++cf) {
        int bcol = cf * 16 + hl;
        float bv = bias[bcol];
        float uu = uvc[bcol];
        float vv = uvc[128 + bcol];
        #pragma unroll
        for (int i = 0; i < 4; ++i) {
            float v = fmaxf(acc0[cf][i] + bv, 0.f);
            ps0[i] += v * uu;
            pt0[i] += v * vv;
            float v1 = fmaxf(acc1[cf][i] + bv, 0.f);
            ps1[i] += v1 * uu;
            pt1[i] += v1 * vv;
        }
    }
    #pragma unroll
    for (int m = 1; m < 16; m <<= 1) {
        #pragma unroll
        for (int i = 0; i < 4; ++i) {
            ps0[i] += __shfl_xor(ps0[i], m, 64);
            pt0[i] += __shfl_xor(pt0[i], m, 64);
            ps1[i] += __shfl_xor(ps1[i], m, 64);
            pt1[i] += __shfl_xor(pt1[i], m, 64);
        }
    }
    if (hl == 0) {
        int rbase0 = g0 * 16 + (lane >> 4) * 4;
        #pragma unroll
        for (int i = 0; i < 4; ++i) {
            s[rbase0 + i] = ps0[i];
            t[rbase0 + i] = pt0[i];
            if (g1ok) {
                s[rbase0 + 16 + i] = ps1[i];
                t[rbase0 + 16 + i] = pt1[i];
            }
        }
    }
}

// scalar mean-gather epilogue: out[i] = mean_j s[col] + t[i] + c
// 16 lanes per node -> 12500 waves of TLP, strided loads, shfl reduce.
__global__ __launch_bounds__(256) void k_sagg2(const float* __restrict__ s,
                                               const float* __restrict__ t,
                                               const float* __restrict__ uvc,
                                               const int* __restrict__ rs,
                                               const int* __restrict__ col,
                                               float* __restrict__ out) {
    const int lane = threadIdx.x & 63;
    const int hl = lane & 15;
    const int node = blockIdx.x * 16 + (threadIdx.x >> 6) * 4 + (lane >> 4);
    // grid is exact (50000 = 3125*16): all lanes active at the shfl below
    const int j0 = rs[node], j1 = rs[node + 1];
    float sm = 0.f;
    for (int j = j0 + hl; j < j1; j += 16) sm += s[col[j]];
    #pragma unroll
    for (int m = 1; m < 16; m <<= 1) sm += __shfl_xor(sm, m, 64);
    if (hl == 0) {
        int deg = j1 - j0;
        out[node] = sm / (float)(deg > 0 ? deg : 1) + t[node] + uvc[256];
    }
}

// ---------------- launch ----------------

extern "C" void kernel_launch(void* const* d_in, const int* in_sizes, int n_in,
                              void* d_out, int out_size, void* d_ws,
                              size_t ws_size, hipStream_t stream) {
    const float* x = (const float*)d_in[0];
    const int* ei = (const int*)d_in[1];
    const int* src = ei;
    const int* dst = ei + N_EDGES;
    const float* wn[3] = {(const float*)d_in[2], (const float*)d_in[5],
                          (const float*)d_in[8]};
    const float* wr[3] = {(const float*)d_in[3], (const float*)d_in[6],
                          (const float*)d_in[9]};
    const float* bs[3] = {(const float*)d_in[4], (const float*)d_in[7],
                          (const float*)d_in[10]};
    const float* wc = (const float*)d_in[11];
    const float* bc = (const float*)d_in[12];
    float* out = (float*)d_out;

    char* ws = (char*)d_ws;
    size_t off = 0;
    auto alloc = [&](size_t bytes) -> void* {
        void* p = (void*)(ws + off);
        off += (bytes + 255) & ~(size_t)255;
        return p;
    };
    const size_t frows = (size_t)(N_NODES + 1) * D;
    int* deg = (int*)alloc(N_NODES * 4);
    int* rs = (int*)alloc((N_NODES + 1) * 4);
    int* rank = (int*)alloc(N_EDGES * 4);
    int* bsum = (int*)alloc(64 * 4);
    int* col = (int*)alloc(N_EDGES * 4);
    unsigned short* f0 = (unsigned short*)alloc(frows * 2);
    unsigned short* f1 = (unsigned short*)alloc(frows * 2);
    unsigned short* f2 = (unsigned short*)alloc(frows * 2);
    unsigned short* Bp = (unsigned short*)alloc(2 * 256 * 128 * 2);
    float* uvc = (float*)alloc(260 * 4);
    float* sbuf = (float*)alloc(N_NODES * 4);
    float* tbuf = (float*)alloc(N_NODES * 4);

    hipMemsetAsync(deg, 0, N_NODES * 4, stream);

    k_big<<<9409, 256, 0, stream>>>(dst, deg, rank, x, wn[0], wr[0], wn[1],
                                    wr[1], wn[2], wr[2], bs[2], wc, bc,
                                    f0, f1, f2, Bp, uvc);

    int nb = (N_NODES + 1023) / 1024;
    k_scan1<<<nb, 1024, 0, stream>>>(deg, rs, bsum);
    k_scan23<<<(N_NODES + 255) / 256, 256, 0, stream>>>(rs, bsum, nb);
    k_fill2<<<(N_EDGES + 255) / 256, 256, 0, stream>>>(src, dst, rs, rank, col);

    const int agg_grid = (N_NODES + 3) / 4;
    const int gemm_grid = ((NGROUPS + 1) / 2 + 3) / 4;
    unsigned short* Bp0 = Bp;
    unsigned short* Bp1 = Bp + 256 * 128;

    // layer 0: in=f0, mean=f1, out=f2 (relu)
    k_agg2<<<agg_grid, 256, 0, stream>>>(f0, rs, col, f1);
    k_gemm<<<gemm_grid, 256, 0, stream>>>(f1, f0, Bp0, bs[0], f2);
    // layer 1 (+ fused layer-2 dots): in=f2, mean=f0 -> s,t directly
    k_agg2<<<agg_grid, 256, 0, stream>>>(f2, rs, col, f0);
    k_gemm_dot<<<gemm_grid, 256, 0, stream>>>(f0, f2, Bp1, bs[1], uvc, sbuf,
                                              tbuf);
    // collapsed layer 2 + classifier: out = mean(s) + t + c
    k_sagg2<<<NGROUPS, 256, 0, stream>>>(sbuf, tbuf, uvc, rs, col, out);
}

// Round 11
// 163.080 us; speedup vs baseline: 1.3453x; 1.0013x over previous
//
#include <hip/hip_runtime.h>

#define N_NODES 50000
#define N_EDGES 800000
#define D 128
#define NGROUPS 3125   // N_NODES / 16
#define NE4 200000     // N_EDGES / 4
#define NB_E4 782      // ceil(200000 / 256)

typedef __attribute__((ext_vector_type(8))) short short8;
typedef __attribute__((ext_vector_type(4))) float f32x4;

__device__ __forceinline__ float bits2f(unsigned int u) {
    union { unsigned int u; float f; } c; c.u = u; return c.f;
}
__device__ __forceinline__ unsigned short f2b(float f) {
    union { float f; unsigned int u; } c; c.f = f;
    unsigned int r = c.u + 0x7fffu + ((c.u >> 16) & 1u);
    return (unsigned short)(r >> 16);
}

// ---- mega-kernel 1: degrank(x4 ILP) | cast | pack W0,W1 | pad | u,v,c ----
// blocks [0,782):      4 edges/thread: rank[e]=atomicAdd(&deg[dst[e]],1)
// blocks [782,7032):   cast x -> f0 (one float4/thread, 1.6M)
// blocks [7032,7064):  pack W0,W1 into MFMA B-frag order (8192 threads)
// block 7064:          zero pad row N_NODES of f0/f1/f2
// block 7065:          u = Wn2@wc, v = Wr2@wc, c = b2.wc + bc

__global__ void k_big(const int* __restrict__ dst, int* __restrict__ deg,
                      int* __restrict__ rank, const float* __restrict__ x,
                      const float* __restrict__ wn0, const float* __restrict__ wr0,
                      const float* __restrict__ wn1, const float* __restrict__ wr1,
                      const float* __restrict__ wn2, const float* __restrict__ wr2,
                      const float* __restrict__ b2, const float* __restrict__ wc,
                      const float* __restrict__ bc,
                      unsigned short* __restrict__ f0,
                      unsigned short* __restrict__ f1,
                      unsigned short* __restrict__ f2,
                      unsigned short* __restrict__ Bp,
                      float* __restrict__ uvc) {
    int b = blockIdx.x;
    if (b < NB_E4) {
        int i = b * 256 + threadIdx.x;
        if (i < NE4) {
            int4 d4 = reinterpret_cast<const int4*>(dst)[i];
            // 4 independent atomic-returns in flight (latency hiding)
            int r0 = atomicAdd(&deg[d4.x], 1);
            int r1 = atomicAdd(&deg[d4.y], 1);
            int r2 = atomicAdd(&deg[d4.z], 1);
            int r3 = atomicAdd(&deg[d4.w], 1);
            reinterpret_cast<int4*>(rank)[i] = make_int4(r0, r1, r2, r3);
        }
    } else if (b < 7032) {
        int i = (b - NB_E4) * 256 + threadIdx.x;
        float4 v = reinterpret_cast<const float4*>(x)[i];
        ushort4 o;
        o.x = f2b(v.x); o.y = f2b(v.y); o.z = f2b(v.z); o.w = f2b(v.w);
        reinterpret_cast<ushort4*>(f0)[i] = o;
    } else if (b < 7064) {
        int t = (b - 7032) * 256 + threadIdx.x;  // exactly 8192 = 2*8*8*64
        int layer = t >> 12;
        int rem = t & 4095;
        int kstep = rem >> 9;
        int cf = (rem >> 6) & 7;
        int lane = t & 63;
        const float* W = (kstep < 4) ? (layer ? wn1 : wn0) : (layer ? wr1 : wr0);
        int kb = kstep * 32 + (lane >> 4) * 8;
        int colv = cf * 16 + (lane & 15);
        int koff = (kstep < 4) ? kb : kb - 128;
        unsigned short* dstp = Bp + (((layer * 64 + kstep * 8 + cf) * 64 + lane) << 3);
        #pragma unroll
        for (int i = 0; i < 8; ++i) dstp[i] = f2b(W[(koff + i) * D + colv]);
    } else if (b == 7064) {
        int t = threadIdx.x;
        if (t < D) {
            f0[(size_t)N_NODES * D + t] = 0;
            f1[(size_t)N_NODES * D + t] = 0;
            f2[(size_t)N_NODES * D + t] = 0;
        }
    } else {
        int t = threadIdx.x;
        if (t < 128) {
            float su = 0.f;
            for (int m = 0; m < 128; ++m) su += wn2[t * D + m] * wc[m];
            uvc[t] = su;
        } else {
            int k = t - 128;
            float sv = 0.f;
            for (int m = 0; m < 128; ++m) sv += wr2[k * D + m] * wc[m];
            uvc[128 + k] = sv;
        }
        if (t == 0) {
            float sc = 0.f;
            for (int m = 0; m < 128; ++m) sc += b2[m] * wc[m];
            uvc[256] = sc + bc[0];
        }
    }
}

// ---------------- CSR scan: wave-shfl block scan (2 barriers) -------------

__global__ void k_scan1(const int* __restrict__ deg, int* __restrict__ rs,
                        int* __restrict__ bsum) {
    __shared__ int wsum[16];
    int tid = threadIdx.x;
    int lane = tid & 63, wid = tid >> 6;
    int i = blockIdx.x * 1024 + tid;
    int v = (i < N_NODES) ? deg[i] : 0;
    int s = v;  // wave-inclusive scan
    #pragma unroll
    for (int off = 1; off < 64; off <<= 1) {
        int t = __shfl_up(s, off, 64);
        if (lane >= off) s += t;
    }
    if (lane == 63) wsum[wid] = s;
    __syncthreads();
    if (tid < 64) {  // wave 0 scans the 16 wave totals (exclusive)
        int wv = (tid < 16) ? wsum[tid] : 0;
        int t = wv;
        #pragma unroll
        for (int off = 1; off < 16; off <<= 1) {
            int u = __shfl_up(t, off, 64);
            if (tid >= off) t += u;
        }
        if (tid < 16) wsum[tid] = t - wv;
    }
    __syncthreads();
    int excl = s - v + wsum[wid];
    if (i < N_NODES) rs[i] = excl;
    if (tid == 1023) bsum[blockIdx.x] = excl + v;  // block total
}

// fused scan2+scan3: every block redoes the cheap 49-element scan
__global__ void k_scan23(int* __restrict__ rs, const int* __restrict__ bsum,
                         int nb) {
    __shared__ int bp[64];
    if (threadIdx.x < 64) {
        int lane = threadIdx.x;  // full wave 0: shfl safe
        int v = (lane < nb) ? bsum[lane] : 0;
        int s = v;
        #pragma unroll
        for (int off = 1; off < 64; off <<= 1) {
            int t = __shfl_up(s, off, 64);
            if (lane >= off) s += t;
        }
        bp[lane] = s - v;  // exclusive
    }
    __syncthreads();
    int i = blockIdx.x * blockDim.x + threadIdx.x;
    if (i < N_NODES) rs[i] += bp[i >> 10];
    if (i == 0) rs[N_NODES] = N_EDGES;
}

// fill with 4-edge ILP: 4 independent rs-gathers + scattered stores in flight
__global__ void k_fill2(const int* __restrict__ src, const int* __restrict__ dst,
                        const int* __restrict__ rs, const int* __restrict__ rank,
                        int* __restrict__ col) {
    int i = blockIdx.x * blockDim.x + threadIdx.x;
    if (i >= NE4) return;
    int4 d4 = reinterpret_cast<const int4*>(dst)[i];
    int4 r4 = reinterpret_cast<const int4*>(rank)[i];
    int4 s4 = reinterpret_cast<const int4*>(src)[i];
    int p0 = rs[d4.x], p1 = rs[d4.y], p2 = rs[d4.z], p3 = rs[d4.w];
    col[p0 + r4.x] = s4.x;
    col[p1 + r4.y] = s4.y;
    col[p2 + r4.z] = s4.z;
    col[p3 + r4.w] = s4.w;
}

// ---------------- mean aggregation: one node per wave (validated r8) ------

#define ACCUM(v)                                                      \
    acc0 += bits2f((v).x << 16); acc1 += bits2f((v).x & 0xffff0000u); \
    acc2 += bits2f((v).y << 16); acc3 += bits2f((v).y & 0xffff0000u); \
    acc4 += bits2f((v).z << 16); acc5 += bits2f((v).z & 0xffff0000u); \
    acc6 += bits2f((v).w << 16); acc7 += bits2f((v).w & 0xffff0000u);

__global__ __launch_bounds__(256) void k_agg2(const unsigned short* __restrict__ h,
                                              const int* __restrict__ rs,
                                              const int* __restrict__ col,
                                              unsigned short* __restrict__ mean) {
    const int lane = threadIdx.x & 63;
    const int node = blockIdx.x * 4 + (threadIdx.x >> 6);
    if (node >= N_NODES) return;
    const int j0 = rs[node], j1 = rs[node + 1];
    const int deg = j1 - j0;
    const int q = lane >> 4;
    const int d8 = (lane & 15) * 8;

    int myc = (j0 + lane < j1) ? col[j0 + lane] : N_NODES;  // pad row: zeros
    const int nfull = deg < 64 ? deg : 64;
    const int nb = (nfull + 15) >> 4;   // wave-uniform batch count

    float acc0 = 0.f, acc1 = 0.f, acc2 = 0.f, acc3 = 0.f;
    float acc4 = 0.f, acc5 = 0.f, acc6 = 0.f, acc7 = 0.f;

    for (int i = 0; i < nb; ++i) {      // uniform trips: shfl always safe
        int t = (i << 4) + q;
        int c0 = __shfl(myc, t, 64);
        int c1 = __shfl(myc, t + 4, 64);
        int c2 = __shfl(myc, t + 8, 64);
        int c3 = __shfl(myc, t + 12, 64);
        uint4 v0 = *(const uint4*)(h + (size_t)c0 * D + d8);
        uint4 v1 = *(const uint4*)(h + (size_t)c1 * D + d8);
        uint4 v2 = *(const uint4*)(h + (size_t)c2 * D + d8);
        uint4 v3 = *(const uint4*)(h + (size_t)c3 * D + d8);
        ACCUM(v0); ACCUM(v1); ACCUM(v2); ACCUM(v3);
    }
    for (int j = j0 + 64 + q; j < j1; j += 4) {  // deg>64 (~never); no shfl
        int c = col[j];
        uint4 v = *(const uint4*)(h + (size_t)c * D + d8);
        ACCUM(v);
    }

    acc0 += __shfl_xor(acc0, 16, 64); acc0 += __shfl_xor(acc0, 32, 64);
    acc1 += __shfl_xor(acc1, 16, 64); acc1 += __shfl_xor(acc1, 32, 64);
    acc2 += __shfl_xor(acc2, 16, 64); acc2 += __shfl_xor(acc2, 32, 64);
    acc3 += __shfl_xor(acc3, 16, 64); acc3 += __shfl_xor(acc3, 32, 64);
    acc4 += __shfl_xor(acc4, 16, 64); acc4 += __shfl_xor(acc4, 32, 64);
    acc5 += __shfl_xor(acc5, 16, 64); acc5 += __shfl_xor(acc5, 32, 64);
    acc6 += __shfl_xor(acc6, 16, 64); acc6 += __shfl_xor(acc6, 32, 64);
    acc7 += __shfl_xor(acc7, 16, 64); acc7 += __shfl_xor(acc7, 32, 64);

    if (lane < 16) {
        float s = 1.0f / (float)(deg > 0 ? deg : 1);
        uint4 o;
        o.x = (unsigned int)f2b(acc0 * s) | ((unsigned int)f2b(acc1 * s) << 16);
        o.y = (unsigned int)f2b(acc2 * s) | ((unsigned int)f2b(acc3 * s) << 16);
        o.z = (unsigned int)f2b(acc4 * s) | ((unsigned int)f2b(acc5 * s) << 16);
        o.w = (unsigned int)f2b(acc6 * s) | ((unsigned int)f2b(acc7 * s) << 16);
        *reinterpret_cast<uint4*>(mean + (size_t)node * D + d8) = o;
    }
}

// ---------------- MFMA GEMM (relu, layer 0): 2 row-groups per wave --------

__global__ __launch_bounds__(256) void k_gemm(
    const unsigned short* __restrict__ Amean, const unsigned short* __restrict__ Ah,
    const unsigned short* __restrict__ Bp, const float* __restrict__ bias,
    unsigned short* __restrict__ outh) {
    int lane = threadIdx.x & 63;
    int w = blockIdx.x * 4 + (threadIdx.x >> 6);
    int g0 = w * 2;
    if (g0 >= NGROUPS) return;
    int g1ok = (g0 + 1 < NGROUPS);
    int hl = lane & 15;
    int klane = (lane >> 4) * 8;
    int arow0 = g0 * 16 + hl;
    int arow1 = g0 * 16 + 16 + hl;
    if (arow1 > N_NODES) arow1 = N_NODES;  // pad row (zeros) when g1 invalid

    f32x4 acc0[8], acc1[8];
    #pragma unroll
    for (int i = 0; i < 8; ++i) { acc0[i] = (f32x4)0.0f; acc1[i] = (f32x4)0.0f; }

    const short8* bpv = reinterpret_cast<const short8*>(Bp);
    #pragma unroll
    for (int kstep = 0; kstep < 8; ++kstep) {
        const unsigned short* Asrc = (kstep < 4) ? Amean : Ah;
        int kk = (kstep & 3) * 32 + klane;
        short8 a0 = *reinterpret_cast<const short8*>(Asrc + (size_t)arow0 * D + kk);
        short8 a1 = *reinterpret_cast<const short8*>(Asrc + (size_t)arow1 * D + kk);
        #pragma unroll
        for (int cf = 0; cf < 8; ++cf) {
            short8 b = bpv[(kstep * 8 + cf) * 64 + lane];
            acc0[cf] = __builtin_amdgcn_mfma_f32_16x16x32_bf16(a0, b, acc0[cf], 0, 0, 0);
            acc1[cf] = __builtin_amdgcn_mfma_f32_16x16x32_bf16(a1, b, acc1[cf], 0, 0, 0);
        }
    }

    int rbase0 = g0 * 16 + (lane >> 4) * 4;
    #pragma unroll
    for (int cf = 0; cf < 8; ++cf) {
        int bcol = cf * 16 + hl;
        float bv = bias[bcol];
        #pragma unroll
        for (int i = 0; i < 4; ++i) {
            float v = fmaxf(acc0[cf][i] + bv, 0.f);
            outh[(size_t)(rbase0 + i) * D + bcol] = f2b(v);
            if (g1ok) {
                float v1 = fmaxf(acc1[cf][i] + bv, 0.f);
                outh[(size_t)(rbase0 + 16 + i) * D + bcol] = f2b(v1);
            }
        }
    }
}

// ---- MFMA GEMM layer 1 + fused dot: s = relu(row).u, t = relu(row).v -----

__global__ __launch_bounds__(256) void k_gemm_dot(
    const unsigned short* __restrict__ Amean, const unsigned short* __restrict__ Ah,
    const unsigned short* __restrict__ Bp, const float* __restrict__ bias,
    const float* __restrict__ uvc, float* __restrict__ s, float* __restrict__ t) {
    int lane = threadIdx.x & 63;
    int w = blockIdx.x * 4 + (threadIdx.x >> 6);
    int g0 = w * 2;
    if (g0 >= NGROUPS) return;
    int g1ok = (g0 + 1 < NGROUPS);
    int hl = lane & 15;
    int klane = (lane >> 4) * 8;
    int arow0 = g0 * 16 + hl;
    int arow1 = g0 * 16 + 16 + hl;
    if (arow1 > N_NODES) arow1 = N_NODES;

    f32x4 acc0[8], acc1[8];
    #pragma unroll
    for (int i = 0; i < 8; ++i) { acc0[i] = (f32x4)0.0f; acc1[i] = (f32x4)0.0f; }

    const short8* bpv = reinterpret_cast<const short8*>(Bp);
    #pragma unroll
    for (int kstep = 0; kstep < 8; ++kstep) {
        const unsigned short* Asrc = (kstep < 4) ? Amean : Ah;
        int kk = (kstep & 3) * 32 + klane;
        short8 a0 = *reinterpret_cast<const short8*>(Asrc + (size_t)arow0 * D + kk);
        short8 a1 = *reinterpret_cast<const short8*>(Asrc + (size_t)arow1 * D + kk);
        #pragma unroll
        for (int cf = 0; cf < 8; ++cf) {
            short8 b = bpv[(kstep * 8 + cf) * 64 + lane];
            acc0[cf] = __builtin_amdgcn_mfma_f32_16x16x32_bf16(a0, b, acc0[cf], 0, 0, 0);
            acc1[cf] = __builtin_amdgcn_mfma_f32_16x16x32_bf16(a1, b, acc1[cf], 0, 0, 0);
        }
    }

    float ps0[4] = {0.f, 0.f, 0.f, 0.f}, pt0[4] = {0.f, 0.f, 0.f, 0.f};
    float ps1[4] = {0.f, 0.f, 0.f, 0.f}, pt1[4] = {0.f, 0.f, 0.f, 0.f};
    #pragma unroll
    for (int cf = 0; cf < 8; ++cf) {
        int bcol = cf * 16 + hl;
        float bv = bias[bcol];
        float uu = uvc[bcol];
        float vv = uvc[128 + bcol];
        #pragma unroll
        for (int i = 0; i < 4; ++i) {
            float v = fmaxf(acc0[cf][i] + bv, 0.f);
            ps0[i] += v * uu;
            pt0[i] += v * vv;
            float v1 = fmaxf(acc1[cf][i] + bv, 0.f);
            ps1[i] += v1 * uu;
            pt1[i] += v1 * vv;
        }
    }
    #pragma unroll
    for (int m = 1; m < 16; m <<= 1) {
        #pragma unroll
        for (int i = 0; i < 4; ++i) {
            ps0[i] += __shfl_xor(ps0[i], m, 64);
            pt0[i] += __shfl_xor(pt0[i], m, 64);
            ps1[i] += __shfl_xor(ps1[i], m, 64);
            pt1[i] += __shfl_xor(pt1[i], m, 64);
        }
    }
    if (hl == 0) {
        int rbase0 = g0 * 16 + (lane >> 4) * 4;
        #pragma unroll
        for (int i = 0; i < 4; ++i) {
            s[rbase0 + i] = ps0[i];
            t[rbase0 + i] = pt0[i];
            if (g1ok) {
                s[rbase0 + 16 + i] = ps1[i];
                t[rbase0 + 16 + i] = pt1[i];
            }
        }
    }
}

// scalar mean-gather epilogue: out[i] = mean_j s[col] + t[i] + c
__global__ __launch_bounds__(256) void k_sagg2(const float* __restrict__ s,
                                               const float* __restrict__ t,
                                               const float* __restrict__ uvc,
                                               const int* __restrict__ rs,
                                               const int* __restrict__ col,
                                               float* __restrict__ out) {
    const int lane = threadIdx.x & 63;
    const int hl = lane & 15;
    const int node = blockIdx.x * 16 + (threadIdx.x >> 6) * 4 + (lane >> 4);
    const int j0 = rs[node], j1 = rs[node + 1];
    float sm = 0.f;
    for (int j = j0 + hl; j < j1; j += 16) sm += s[col[j]];
    #pragma unroll
    for (int m = 1; m < 16; m <<= 1) sm += __shfl_xor(sm, m, 64);
    if (hl == 0) {
        int deg = j1 - j0;
        out[node] = sm / (float)(deg > 0 ? deg : 1) + t[node] + uvc[256];
    }
}

// ---------------- launch ----------------

extern "C" void kernel_launch(void* const* d_in, const int* in_sizes, int n_in,
                              void* d_out, int out_size, void* d_ws,
                              size_t ws_size, hipStream_t stream) {
    const float* x = (const float*)d_in[0];
    const int* ei = (const int*)d_in[1];
    const int* src = ei;
    const int* dst = ei + N_EDGES;
    const float* wn[3] = {(const float*)d_in[2], (const float*)d_in[5],
                          (const float*)d_in[8]};
    const float* wr[3] = {(const float*)d_in[3], (const float*)d_in[6],
                          (const float*)d_in[9]};
    const float* bs[3] = {(const float*)d_in[4], (const float*)d_in[7],
                          (const float*)d_in[10]};
    const float* wc = (const float*)d_in[11];
    const float* bc = (const float*)d_in[12];
    float* out = (float*)d_out;

    char* ws = (char*)d_ws;
    size_t off = 0;
    auto alloc = [&](size_t bytes) -> void* {
        void* p = (void*)(ws + off);
        off += (bytes + 255) & ~(size_t)255;
        return p;
    };
    const size_t frows = (size_t)(N_NODES + 1) * D;
    int* deg = (int*)alloc(N_NODES * 4);
    int* rs = (int*)alloc((N_NODES + 1) * 4);
    int* rank = (int*)alloc(N_EDGES * 4);
    int* bsum = (int*)alloc(64 * 4);
    int* col = (int*)alloc(N_EDGES * 4);
    unsigned short* f0 = (unsigned short*)alloc(frows * 2);
    unsigned short* f1 = (unsigned short*)alloc(frows * 2);
    unsigned short* f2 = (unsigned short*)alloc(frows * 2);
    unsigned short* Bp = (unsigned short*)alloc(2 * 256 * 128 * 2);
    float* uvc = (float*)alloc(260 * 4);
    float* sbuf = (float*)alloc(N_NODES * 4);
    float* tbuf = (float*)alloc(N_NODES * 4);

    hipMemsetAsync(deg, 0, N_NODES * 4, stream);

    k_big<<<7066, 256, 0, stream>>>(dst, deg, rank, x, wn[0], wr[0], wn[1],
                                    wr[1], wn[2], wr[2], bs[2], wc, bc,
                                    f0, f1, f2, Bp, uvc);

    int nb = (N_NODES + 1023) / 1024;
    k_scan1<<<nb, 1024, 0, stream>>>(deg, rs, bsum);
    k_scan23<<<(N_NODES + 255) / 256, 256, 0, stream>>>(rs, bsum, nb);
    k_fill2<<<NB_E4, 256, 0, stream>>>(src, dst, rs, rank, col);

    const int agg_grid = (N_NODES + 3) / 4;
    const int gemm_grid = ((NGROUPS + 1) / 2 + 3) / 4;
    unsigned short* Bp0 = Bp;
    unsigned short* Bp1 = Bp + 256 * 128;

    // layer 0: in=f0, mean=f1, out=f2 (relu)
    k_agg2<<<agg_grid, 256, 0, stream>>>(f0, rs, col, f1);
    k_gemm<<<gemm_grid, 256, 0, stream>>>(f1, f0, Bp0, bs[0], f2);
    // layer 1 (+ fused layer-2 dots): in=f2, mean=f0 -> s,t directly
    k_agg2<<<agg_grid, 256, 0, stream>>>(f2, rs, col, f0);
    k_gemm_dot<<<gemm_grid, 256, 0, stream>>>(f0, f2, Bp1, bs[1], uvc, sbuf,
                                              tbuf);
    // collapsed layer 2 + classifier: out = mean(s) + t + c
    k_sagg2<<<NGROUPS, 256, 0, stream>>>(sbuf, tbuf, uvc, rs, col, out);
}

// Round 12
// 161.635 us; speedup vs baseline: 1.3573x; 1.0089x over previous
//
#include <hip/hip_runtime.h>

#define N_NODES 50000
#define N_EDGES 800000
#define D 128
#define NGROUPS 3125   // N_NODES / 16
#define NE4 200000     // N_EDGES / 4
#define NB_E4 782      // ceil(200000 / 256)
#define NCOPY 8        // privatized degree histograms

typedef __attribute__((ext_vector_type(8))) short short8;
typedef __attribute__((ext_vector_type(4))) float f32x4;

__device__ __forceinline__ float bits2f(unsigned int u) {
    union { unsigned int u; float f; } c; c.u = u; return c.f;
}
__device__ __forceinline__ unsigned short f2b(float f) {
    union { float f; unsigned int u; } c; c.f = f;
    unsigned int r = c.u + 0x7fffu + ((c.u >> 16) & 1u);
    return (unsigned short)(r >> 16);
}

// ---- mega-kernel 1: degrank(8-copy) | cast | pack W0,W1 | pad | u,v,c ----
// blocks [0,3125):     rank[e] = atomicAdd(&deg8[(b&7)*N + dst[e]], 1)
//                      (8 privatized copies -> 8x less per-line contention)
// blocks [3125,9375):  cast x -> f0 (one float4/thread, 1.6M)
// blocks [9375,9407):  pack W0,W1 into MFMA B-frag order (8192 threads)
// block 9407:          zero pad row N_NODES of f0/f1/f2
// block 9408:          u = Wn2@wc, v = Wr2@wc, c = b2.wc + bc

__global__ void k_big(const int* __restrict__ dst, int* __restrict__ deg8,
                      int* __restrict__ rank, const float* __restrict__ x,
                      const float* __restrict__ wn0, const float* __restrict__ wr0,
                      const float* __restrict__ wn1, const float* __restrict__ wr1,
                      const float* __restrict__ wn2, const float* __restrict__ wr2,
                      const float* __restrict__ b2, const float* __restrict__ wc,
                      const float* __restrict__ bc,
                      unsigned short* __restrict__ f0,
                      unsigned short* __restrict__ f1,
                      unsigned short* __restrict__ f2,
                      unsigned short* __restrict__ Bp,
                      float* __restrict__ uvc) {
    int b = blockIdx.x;
    if (b < 3125) {
        int e = b * 256 + threadIdx.x;
        int k = b & (NCOPY - 1);
        rank[e] = atomicAdd(&deg8[k * N_NODES + dst[e]], 1);
    } else if (b < 9375) {
        int i = (b - 3125) * 256 + threadIdx.x;
        float4 v = reinterpret_cast<const float4*>(x)[i];
        ushort4 o;
        o.x = f2b(v.x); o.y = f2b(v.y); o.z = f2b(v.z); o.w = f2b(v.w);
        reinterpret_cast<ushort4*>(f0)[i] = o;
    } else if (b < 9407) {
        int t = (b - 9375) * 256 + threadIdx.x;  // exactly 8192 = 2*8*8*64
        int layer = t >> 12;
        int rem = t & 4095;
        int kstep = rem >> 9;
        int cf = (rem >> 6) & 7;
        int lane = t & 63;
        const float* W = (kstep < 4) ? (layer ? wn1 : wn0) : (layer ? wr1 : wr0);
        int kb = kstep * 32 + (lane >> 4) * 8;
        int colv = cf * 16 + (lane & 15);
        int koff = (kstep < 4) ? kb : kb - 128;
        unsigned short* dstp = Bp + (((layer * 64 + kstep * 8 + cf) * 64 + lane) << 3);
        #pragma unroll
        for (int i = 0; i < 8; ++i) dstp[i] = f2b(W[(koff + i) * D + colv]);
    } else if (b == 9407) {
        int t = threadIdx.x;
        if (t < D) {
            f0[(size_t)N_NODES * D + t] = 0;
            f1[(size_t)N_NODES * D + t] = 0;
            f2[(size_t)N_NODES * D + t] = 0;
        }
    } else {
        int t = threadIdx.x;
        if (t < 128) {
            float su = 0.f;
            for (int m = 0; m < 128; ++m) su += wn2[t * D + m] * wc[m];
            uvc[t] = su;
        } else {
            int k = t - 128;
            float sv = 0.f;
            for (int m = 0; m < 128; ++m) sv += wr2[k * D + m] * wc[m];
            uvc[128 + k] = sv;
        }
        if (t == 0) {
            float sc = 0.f;
            for (int m = 0; m < 128; ++m) sc += b2[m] * wc[m];
            uvc[256] = sc + bc[0];
        }
    }
}

// ---- CSR scan: fold 8 copies -> per-copy offsets (in place) + block scan --

__global__ void k_scan1(int* __restrict__ deg8, int* __restrict__ rs,
                        int* __restrict__ bsum) {
    __shared__ int wsum[16];
    int tid = threadIdx.x;
    int lane = tid & 63, wid = tid >> 6;
    int i = blockIdx.x * 1024 + tid;
    int v = 0;
    if (i < N_NODES) {
        int pref[NCOPY];
        #pragma unroll
        for (int k = 0; k < NCOPY; ++k) {
            pref[k] = v;
            v += deg8[k * N_NODES + i];
        }
        #pragma unroll
        for (int k = 0; k < NCOPY; ++k) deg8[k * N_NODES + i] = pref[k];
    }
    int s = v;  // wave-inclusive scan
    #pragma unroll
    for (int off = 1; off < 64; off <<= 1) {
        int t = __shfl_up(s, off, 64);
        if (lane >= off) s += t;
    }
    if (lane == 63) wsum[wid] = s;
    __syncthreads();
    if (tid < 64) {  // wave 0 scans the 16 wave totals (exclusive)
        int wv = (tid < 16) ? wsum[tid] : 0;
        int t = wv;
        #pragma unroll
        for (int off = 1; off < 16; off <<= 1) {
            int u = __shfl_up(t, off, 64);
            if (tid >= off) t += u;
        }
        if (tid < 16) wsum[tid] = t - wv;
    }
    __syncthreads();
    int excl = s - v + wsum[wid];
    if (i < N_NODES) rs[i] = excl;
    if (tid == 1023) bsum[blockIdx.x] = excl + v;  // block total
}

// fused scan2+scan3: every block redoes the cheap 49-element scan
__global__ void k_scan23(int* __restrict__ rs, const int* __restrict__ bsum,
                         int nb) {
    __shared__ int bp[64];
    if (threadIdx.x < 64) {
        int lane = threadIdx.x;  // full wave 0: shfl safe
        int v = (lane < nb) ? bsum[lane] : 0;
        int s = v;
        #pragma unroll
        for (int off = 1; off < 64; off <<= 1) {
            int t = __shfl_up(s, off, 64);
            if (lane >= off) s += t;
        }
        bp[lane] = s - v;  // exclusive
    }
    __syncthreads();
    int i = blockIdx.x * blockDim.x + threadIdx.x;
    if (i < N_NODES) rs[i] += bp[i >> 10];
    if (i == 0) rs[N_NODES] = N_EDGES;
}

// fill: pos = rs[dst] + copy_offset[k][dst] + rank. 4 edges/thread; the 4
// edges of one int4 share the same k (= (i>>6)&7, since 256 | edge-block).
__global__ void k_fill2(const int* __restrict__ src, const int* __restrict__ dst,
                        const int* __restrict__ rs, const int* __restrict__ deg8,
                        const int* __restrict__ rank, int* __restrict__ col) {
    int i = blockIdx.x * blockDim.x + threadIdx.x;
    if (i >= NE4) return;
    int k = (i >> 6) & (NCOPY - 1);
    const int* off8 = deg8 + k * N_NODES;
    int4 d4 = reinterpret_cast<const int4*>(dst)[i];
    int4 r4 = reinterpret_cast<const int4*>(rank)[i];
    int4 s4 = reinterpret_cast<const int4*>(src)[i];
    int p0 = rs[d4.x] + off8[d4.x];
    int p1 = rs[d4.y] + off8[d4.y];
    int p2 = rs[d4.z] + off8[d4.z];
    int p3 = rs[d4.w] + off8[d4.w];
    col[p0 + r4.x] = s4.x;
    col[p1 + r4.y] = s4.y;
    col[p2 + r4.z] = s4.z;
    col[p3 + r4.w] = s4.w;
}

// ---------------- mean aggregation: one node per wave (validated r8) ------

#define ACCUM(v)                                                      \
    acc0 += bits2f((v).x << 16); acc1 += bits2f((v).x & 0xffff0000u); \
    acc2 += bits2f((v).y << 16); acc3 += bits2f((v).y & 0xffff0000u); \
    acc4 += bits2f((v).z << 16); acc5 += bits2f((v).z & 0xffff0000u); \
    acc6 += bits2f((v).w << 16); acc7 += bits2f((v).w & 0xffff0000u);

__global__ __launch_bounds__(256) void k_agg2(const unsigned short* __restrict__ h,
                                              const int* __restrict__ rs,
                                              const int* __restrict__ col,
                                              unsigned short* __restrict__ mean) {
    const int lane = threadIdx.x & 63;
    const int node = blockIdx.x * 4 + (threadIdx.x >> 6);
    if (node >= N_NODES) return;
    const int j0 = rs[node], j1 = rs[node + 1];
    const int deg = j1 - j0;
    const int q = lane >> 4;
    const int d8 = (lane & 15) * 8;

    int myc = (j0 + lane < j1) ? col[j0 + lane] : N_NODES;  // pad row: zeros
    const int nfull = deg < 64 ? deg : 64;
    const int nb = (nfull + 15) >> 4;   // wave-uniform batch count

    float acc0 = 0.f, acc1 = 0.f, acc2 = 0.f, acc3 = 0.f;
    float acc4 = 0.f, acc5 = 0.f, acc6 = 0.f, acc7 = 0.f;

    for (int i = 0; i < nb; ++i) {      // uniform trips: shfl always safe
        int t = (i << 4) + q;
        int c0 = __shfl(myc, t, 64);
        int c1 = __shfl(myc, t + 4, 64);
        int c2 = __shfl(myc, t + 8, 64);
        int c3 = __shfl(myc, t + 12, 64);
        uint4 v0 = *(const uint4*)(h + (size_t)c0 * D + d8);
        uint4 v1 = *(const uint4*)(h + (size_t)c1 * D + d8);
        uint4 v2 = *(const uint4*)(h + (size_t)c2 * D + d8);
        uint4 v3 = *(const uint4*)(h + (size_t)c3 * D + d8);
        ACCUM(v0); ACCUM(v1); ACCUM(v2); ACCUM(v3);
    }
    for (int j = j0 + 64 + q; j < j1; j += 4) {  // deg>64 (~never); no shfl
        int c = col[j];
        uint4 v = *(const uint4*)(h + (size_t)c * D + d8);
        ACCUM(v);
    }

    acc0 += __shfl_xor(acc0, 16, 64); acc0 += __shfl_xor(acc0, 32, 64);
    acc1 += __shfl_xor(acc1, 16, 64); acc1 += __shfl_xor(acc1, 32, 64);
    acc2 += __shfl_xor(acc2, 16, 64); acc2 += __shfl_xor(acc2, 32, 64);
    acc3 += __shfl_xor(acc3, 16, 64); acc3 += __shfl_xor(acc3, 32, 64);
    acc4 += __shfl_xor(acc4, 16, 64); acc4 += __shfl_xor(acc4, 32, 64);
    acc5 += __shfl_xor(acc5, 16, 64); acc5 += __shfl_xor(acc5, 32, 64);
    acc6 += __shfl_xor(acc6, 16, 64); acc6 += __shfl_xor(acc6, 32, 64);
    acc7 += __shfl_xor(acc7, 16, 64); acc7 += __shfl_xor(acc7, 32, 64);

    if (lane < 16) {
        float s = 1.0f / (float)(deg > 0 ? deg : 1);
        uint4 o;
        o.x = (unsigned int)f2b(acc0 * s) | ((unsigned int)f2b(acc1 * s) << 16);
        o.y = (unsigned int)f2b(acc2 * s) | ((unsigned int)f2b(acc3 * s) << 16);
        o.z = (unsigned int)f2b(acc4 * s) | ((unsigned int)f2b(acc5 * s) << 16);
        o.w = (unsigned int)f2b(acc6 * s) | ((unsigned int)f2b(acc7 * s) << 16);
        *reinterpret_cast<uint4*>(mean + (size_t)node * D + d8) = o;
    }
}

// ---------------- MFMA GEMM (relu, layer 0): 2 row-groups per wave --------

__global__ __launch_bounds__(256) void k_gemm(
    const unsigned short* __restrict__ Amean, const unsigned short* __restrict__ Ah,
    const unsigned short* __restrict__ Bp, const float* __restrict__ bias,
    unsigned short* __restrict__ outh) {
    int lane = threadIdx.x & 63;
    int w = blockIdx.x * 4 + (threadIdx.x >> 6);
    int g0 = w * 2;
    if (g0 >= NGROUPS) return;
    int g1ok = (g0 + 1 < NGROUPS);
    int hl = lane & 15;
    int klane = (lane >> 4) * 8;
    int arow0 = g0 * 16 + hl;
    int arow1 = g0 * 16 + 16 + hl;
    if (arow1 > N_NODES) arow1 = N_NODES;  // pad row (zeros) when g1 invalid

    f32x4 acc0[8], acc1[8];
    #pragma unroll
    for (int i = 0; i < 8; ++i) { acc0[i] = (f32x4)0.0f; acc1[i] = (f32x4)0.0f; }

    const short8* bpv = reinterpret_cast<const short8*>(Bp);
    #pragma unroll
    for (int kstep = 0; kstep < 8; ++kstep) {
        const unsigned short* Asrc = (kstep < 4) ? Amean : Ah;
        int kk = (kstep & 3) * 32 + klane;
        short8 a0 = *reinterpret_cast<const short8*>(Asrc + (size_t)arow0 * D + kk);
        short8 a1 = *reinterpret_cast<const short8*>(Asrc + (size_t)arow1 * D + kk);
        #pragma unroll
        for (int cf = 0; cf < 8; ++cf) {
            short8 b = bpv[(kstep * 8 + cf) * 64 + lane];
            acc0[cf] = __builtin_amdgcn_mfma_f32_16x16x32_bf16(a0, b, acc0[cf], 0, 0, 0);
            acc1[cf] = __builtin_amdgcn_mfma_f32_16x16x32_bf16(a1, b, acc1[cf], 0, 0, 0);
        }
    }

    int rbase0 = g0 * 16 + (lane >> 4) * 4;
    #pragma unroll
    for (int cf = 0; cf < 8; ++cf) {
        int bcol = cf * 16 + hl;
        float bv = bias[bcol];
        #pragma unroll
        for (int i = 0; i < 4; ++i) {
            float v = fmaxf(acc0[cf][i] + bv, 0.f);
            outh[(size_t)(rbase0 + i) * D + bcol] = f2b(v);
            if (g1ok) {
                float v1 = fmaxf(acc1[cf][i] + bv, 0.f);
                outh[(size_t)(rbase0 + 16 + i) * D + bcol] = f2b(v1);
            }
        }
    }
}

// ---- MFMA GEMM layer 1 + fused dot: s = relu(row).u, t = relu(row).v -----

__global__ __launch_bounds__(256) void k_gemm_dot(
    const unsigned short* __restrict__ Amean, const unsigned short* __restrict__ Ah,
    const unsigned short* __restrict__ Bp, const float* __restrict__ bias,
    const float* __restrict__ uvc, float* __restrict__ s, float* __restrict__ t) {
    int lane = threadIdx.x & 63;
    int w = blockIdx.x * 4 + (threadIdx.x >> 6);
    int g0 = w * 2;
    if (g0 >= NGROUPS) return;
    int g1ok = (g0 + 1 < NGROUPS);
    int hl = lane & 15;
    int klane = (lane >> 4) * 8;
    int arow0 = g0 * 16 + hl;
    int arow1 = g0 * 16 + 16 + hl;
    if (arow1 > N_NODES) arow1 = N_NODES;

    f32x4 acc0[8], acc1[8];
    #pragma unroll
    for (int i = 0; i < 8; ++i) { acc0[i] = (f32x4)0.0f; acc1[i] = (f32x4)0.0f; }

    const short8* bpv = reinterpret_cast<const short8*>(Bp);
    #pragma unroll
    for (int kstep = 0; kstep < 8; ++kstep) {
        const unsigned short* Asrc = (kstep < 4) ? Amean : Ah;
        int kk = (kstep & 3) * 32 + klane;
        short8 a0 = *reinterpret_cast<const short8*>(Asrc + (size_t)arow0 * D + kk);
        short8 a1 = *reinterpret_cast<const short8*>(Asrc + (size_t)arow1 * D + kk);
        #pragma unroll
        for (int cf = 0; cf < 8; ++cf) {
            short8 b = bpv[(kstep * 8 + cf) * 64 + lane];
            acc0[cf] = __builtin_amdgcn_mfma_f32_16x16x32_bf16(a0, b, acc0[cf], 0, 0, 0);
            acc1[cf] = __builtin_amdgcn_mfma_f32_16x16x32_bf16(a1, b, acc1[cf], 0, 0, 0);
        }
    }

    float ps0[4] = {0.f, 0.f, 0.f, 0.f}, pt0[4] = {0.f, 0.f, 0.f, 0.f};
    float ps1[4] = {0.f, 0.f, 0.f, 0.f}, pt1[4] = {0.f, 0.f, 0.f, 0.f};
    #pragma unroll
    for (int cf = 0; cf < 8; ++cf) {
        int bcol = cf * 16 + hl;
        float bv = bias[bcol];
        float uu = uvc[bcol];
        float vv = uvc[128 + bcol];
        #pragma unroll
        for (int i = 0; i < 4; ++i) {
            float v = fmaxf(acc0[cf][i] + bv, 0.f);
            ps0[i] += v * uu;
            pt0[i] += v * vv;
            float v1 = fmaxf(acc1[cf][i] + bv, 0.f);
            ps1[i] += v1 * uu;
            pt1[i] += v1 * vv;
        }
    }
    #pragma unroll
    for (int m = 1; m < 16; m <<= 1) {
        #pragma unroll
        for (int i = 0; i < 4; ++i) {
            ps0[i] += __shfl_xor(ps0[i], m, 64);
            pt0[i] += __shfl_xor(pt0[i], m, 64);
            ps1[i] += __shfl_xor(ps1[i], m, 64);
            pt1[i] += __shfl_xor(pt1[i], m, 64);
        }
    }
    if (hl == 0) {
        int rbase0 = g0 * 16 + (lane >> 4) * 4;
        #pragma unroll
        for (int i = 0; i < 4; ++i) {
            s[rbase0 + i] = ps0[i];
            t[rbase0 + i] = pt0[i];
            if (g1ok) {
                s[rbase0 + 16 + i] = ps1[i];
                t[rbase0 + 16 + i] = pt1[i];
            }
        }
    }
}

// scalar mean-gather epilogue: out[i] = mean_j s[col] + t[i] + c
__global__ __launch_bounds__(256) void k_sagg2(const float* __restrict__ s,
                                               const float* __restrict__ t,
                                               const float* __restrict__ uvc,
                                               const int* __restrict__ rs,
                                               const int* __restrict__ col,
                                               float* __restrict__ out) {
    const int lane = threadIdx.x & 63;
    const int hl = lane & 15;
    const int node = blockIdx.x * 16 + (threadIdx.x >> 6) * 4 + (lane >> 4);
    const int j0 = rs[node], j1 = rs[node + 1];
    float sm = 0.f;
    for (int j = j0 + hl; j < j1; j += 16) sm += s[col[j]];
    #pragma unroll
    for (int m = 1; m < 16; m <<= 1) sm += __shfl_xor(sm, m, 64);
    if (hl == 0) {
        int deg = j1 - j0;
        out[node] = sm / (float)(deg > 0 ? deg : 1) + t[node] + uvc[256];
    }
}

// ---------------- launch ----------------

extern "C" void kernel_launch(void* const* d_in, const int* in_sizes, int n_in,
                              void* d_out, int out_size, void* d_ws,
                              size_t ws_size, hipStream_t stream) {
    const float* x = (const float*)d_in[0];
    const int* ei = (const int*)d_in[1];
    const int* src = ei;
    const int* dst = ei + N_EDGES;
    const float* wn[3] = {(const float*)d_in[2], (const float*)d_in[5],
                          (const float*)d_in[8]};
    const float* wr[3] = {(const float*)d_in[3], (const float*)d_in[6],
                          (const float*)d_in[9]};
    const float* bs[3] = {(const float*)d_in[4], (const float*)d_in[7],
                          (const float*)d_in[10]};
    const float* wc = (const float*)d_in[11];
    const float* bc = (const float*)d_in[12];
    float* out = (float*)d_out;

    char* ws = (char*)d_ws;
    size_t off = 0;
    auto alloc = [&](size_t bytes) -> void* {
        void* p = (void*)(ws + off);
        off += (bytes + 255) & ~(size_t)255;
        return p;
    };
    const size_t frows = (size_t)(N_NODES + 1) * D;
    int* deg8 = (int*)alloc((size_t)NCOPY * N_NODES * 4);  // -> copy offsets
    int* rs = (int*)alloc((N_NODES + 1) * 4);
    int* rank = (int*)alloc(N_EDGES * 4);
    int* bsum = (int*)alloc(64 * 4);
    int* col = (int*)alloc(N_EDGES * 4);
    unsigned short* f0 = (unsigned short*)alloc(frows * 2);
    unsigned short* f1 = (unsigned short*)alloc(frows * 2);
    unsigned short* f2 = (unsigned short*)alloc(frows * 2);
    unsigned short* Bp = (unsigned short*)alloc(2 * 256 * 128 * 2);
    float* uvc = (float*)alloc(260 * 4);
    float* sbuf = (float*)alloc(N_NODES * 4);
    float* tbuf = (float*)alloc(N_NODES * 4);

    hipMemsetAsync(deg8, 0, (size_t)NCOPY * N_NODES * 4, stream);

    k_big<<<9409, 256, 0, stream>>>(dst, deg8, rank, x, wn[0], wr[0], wn[1],
                                    wr[1], wn[2], wr[2], bs[2], wc, bc,
                                    f0, f1, f2, Bp, uvc);

    int nb = (N_NODES + 1023) / 1024;
    k_scan1<<<nb, 1024, 0, stream>>>(deg8, rs, bsum);
    k_scan23<<<(N_NODES + 255) / 256, 256, 0, stream>>>(rs, bsum, nb);
    k_fill2<<<NB_E4, 256, 0, stream>>>(src, dst, rs, deg8, rank, col);

    const int agg_grid = (N_NODES + 3) / 4;
    const int gemm_grid = ((NGROUPS + 1) / 2 + 3) / 4;
    unsigned short* Bp0 = Bp;
    unsigned short* Bp1 = Bp + 256 * 128;

    // layer 0: in=f0, mean=f1, out=f2 (relu)
    k_agg2<<<agg_grid, 256, 0, stream>>>(f0, rs, col, f1);
    k_gemm<<<gemm_grid, 256, 0, stream>>>(f1, f0, Bp0, bs[0], f2);
    // layer 1 (+ fused layer-2 dots): in=f2, mean=f0 -> s,t directly
    k_agg2<<<agg_grid, 256, 0, stream>>>(f2, rs, col, f0);
    k_gemm_dot<<<gemm_grid, 256, 0, stream>>>(f0, f2, Bp1, bs[1], uvc, sbuf,
                                              tbuf);
    // collapsed layer 2 + classifier: out = mean(s) + t + c
    k_sagg2<<<NGROUPS, 256, 0, stream>>>(sbuf, tbuf, uvc, rs, col, out);
}

// Round 13
// 140.124 us; speedup vs baseline: 1.5657x; 1.1535x over previous
//
#include <hip/hip_runtime.h>

#define N_NODES 50000
#define N_EDGES 800000
#define D 128
#define NGROUPS 3125   // N_NODES / 16
#define NBUK 256       // node buckets
#define NPB 196        // nodes per bucket (256*196 = 50176 >= 50001)
#define EPB 2048       // edges per histogram/scatter block
#define NBLK 391       // ceil(N_EDGES / EPB)
#define LTOT (NBUK * NBLK)  // 100096 scan cells
#define NSCB 98        // ceil(LTOT / 1024)

typedef __attribute__((ext_vector_type(8))) short short8;
typedef __attribute__((ext_vector_type(4))) float f32x4;

__device__ __forceinline__ float bits2f(unsigned int u) {
    union { unsigned int u; float f; } c; c.u = u; return c.f;
}
__device__ __forceinline__ unsigned short f2b(float f) {
    union { float f; unsigned int u; } c; c.f = f;
    unsigned int r = c.u + 0x7fffu + ((c.u >> 16) & 1u);
    return (unsigned short)(r >> 16);
}

// ---- mega-kernel 1: bucket-histogram | cast | pack W0,W1 | pad | u,v,c ----
// blocks [0,391):      LDS 256-bucket histogram of dst (2048 edges/block),
//                      cnt[block][bucket] written coalesced. NO global atomics.
// blocks [391,6641):   cast x -> f0 (one float4/thread, 1.6M)
// blocks [6641,6673):  pack W0,W1 into MFMA B-frag order (8192 threads)
// block 6673:          zero pad row N_NODES of f0/f1/f2
// block 6674:          u = Wn2@wc, v = Wr2@wc, c = b2.wc + bc

__global__ __launch_bounds__(256) void k_big(
    const int* __restrict__ dst, int* __restrict__ cnt,
    const float* __restrict__ x,
    const float* __restrict__ wn0, const float* __restrict__ wr0,
    const float* __restrict__ wn1, const float* __restrict__ wr1,
    const float* __restrict__ wn2, const float* __restrict__ wr2,
    const float* __restrict__ b2, const float* __restrict__ wc,
    const float* __restrict__ bc,
    unsigned short* __restrict__ f0, unsigned short* __restrict__ f1,
    unsigned short* __restrict__ f2, unsigned short* __restrict__ Bp,
    float* __restrict__ uvc) {
    __shared__ int lc[NBUK];
    int b = blockIdx.x;
    int tid = threadIdx.x;
    if (b < NBLK) {
        lc[tid] = 0;
        __syncthreads();
        #pragma unroll
        for (int k = 0; k < 8; ++k) {
            int e = b * EPB + k * 256 + tid;
            if (e < N_EDGES) atomicAdd(&lc[dst[e] / NPB], 1);  // LDS atomic
        }
        __syncthreads();
        cnt[b * NBUK + tid] = lc[tid];
    } else if (b < 6641) {
        int i = (b - NBLK) * 256 + tid;
        float4 v = reinterpret_cast<const float4*>(x)[i];
        ushort4 o;
        o.x = f2b(v.x); o.y = f2b(v.y); o.z = f2b(v.z); o.w = f2b(v.w);
        reinterpret_cast<ushort4*>(f0)[i] = o;
    } else if (b < 6673) {
        int t = (b - 6641) * 256 + tid;  // exactly 8192 = 2*8*8*64
        int layer = t >> 12;
        int rem = t & 4095;
        int kstep = rem >> 9;
        int cf = (rem >> 6) & 7;
        int lane = t & 63;
        const float* W = (kstep < 4) ? (layer ? wn1 : wn0) : (layer ? wr1 : wr0);
        int kb = kstep * 32 + (lane >> 4) * 8;
        int colv = cf * 16 + (lane & 15);
        int koff = (kstep < 4) ? kb : kb - 128;
        unsigned short* dstp = Bp + (((layer * 64 + kstep * 8 + cf) * 64 + lane) << 3);
        #pragma unroll
        for (int i = 0; i < 8; ++i) dstp[i] = f2b(W[(koff + i) * D + colv]);
    } else if (b == 6673) {
        if (tid < D) {
            f0[(size_t)N_NODES * D + tid] = 0;
            f1[(size_t)N_NODES * D + tid] = 0;
            f2[(size_t)N_NODES * D + tid] = 0;
        }
    } else {
        if (tid < 128) {
            float su = 0.f;
            for (int m = 0; m < 128; ++m) su += wn2[tid * D + m] * wc[m];
            uvc[tid] = su;
        } else {
            int k = tid - 128;
            float sv = 0.f;
            for (int m = 0; m < 128; ++m) sv += wr2[k * D + m] * wc[m];
            uvc[128 + k] = sv;
        }
        if (tid == 0) {
            float sc0 = 0.f;
            for (int m = 0; m < 128; ++m) sc0 += b2[m] * wc[m];
            uvc[256] = sc0 + bc[0];
        }
    }
}

// ---- scanA: exclusive scan of cnt in bucket-major cell order -------------
// cell L = bucket*NBLK + block, value cnt[block*NBUK + bucket]. Validated
// r11 wave-scan structure (shfl + 16 wave-sums).

__global__ void k_scanA(const int* __restrict__ cnt, int* __restrict__ sc,
                        int* __restrict__ bsumA) {
    __shared__ int wsum[16];
    int tid = threadIdx.x;
    int lane = tid & 63, wid = tid >> 6;
    int L = blockIdx.x * 1024 + tid;
    int v = 0;
    if (L < LTOT) {
        int bkt = L / NBLK;
        int j = L - bkt * NBLK;
        v = cnt[j * NBUK + bkt];
    }
    int s = v;
    #pragma unroll
    for (int off = 1; off < 64; off <<= 1) {
        int t = __shfl_up(s, off, 64);
        if (lane >= off) s += t;
    }
    if (lane == 63) wsum[wid] = s;
    __syncthreads();
    if (tid < 64) {
        int wv = (tid < 16) ? wsum[tid] : 0;
        int t = wv;
        #pragma unroll
        for (int off = 1; off < 16; off <<= 1) {
            int u = __shfl_up(t, off, 64);
            if (tid >= off) t += u;
        }
        if (tid < 16) wsum[tid] = t - wv;
    }
    __syncthreads();
    int excl = s - v + wsum[wid];
    if (L < LTOT) sc[L] = excl;
    if (tid == 1023) bsumA[blockIdx.x] = excl + v;
}

// ---- scatter: group edges by bucket via LDS cursors ----------------------
// Block j re-reads its 2048 edges; cursor[b] starts at the global offset of
// cell (b, j); claims are LDS atomics. Writes (dst,src) bucket-grouped.

__global__ __launch_bounds__(256) void k_scatter(
    const int* __restrict__ src, const int* __restrict__ dst,
    const int* __restrict__ sc, const int* __restrict__ bsumA,
    int* __restrict__ ed, int* __restrict__ es) {
    __shared__ int sb[128];
    __shared__ int cursor[NBUK];
    int tid = threadIdx.x, j = blockIdx.x;
    if (tid < 128) sb[tid] = (tid < NSCB) ? bsumA[tid] : 0;
    __syncthreads();
    for (int off = 1; off < 128; off <<= 1) {  // LDS Hillis-Steele (r1-validated)
        int t = (tid < 128 && tid >= off) ? sb[tid - off] : 0;
        __syncthreads();
        if (tid < 128) sb[tid] += t;
        __syncthreads();
    }
    int L = tid * NBLK + j;
    int idx = L >> 10;
    cursor[tid] = sc[L] + (idx ? sb[idx - 1] : 0);
    __syncthreads();
    #pragma unroll
    for (int k = 0; k < 8; ++k) {
        int e = j * EPB + k * 256 + tid;
        if (e < N_EDGES) {
            int d = dst[e];
            int p = atomicAdd(&cursor[d / NPB], 1);  // LDS atomic
            ed[p] = d;
            es[p] = src[e];
        }
    }
}

// ---- bucket: per-bucket rank + rs + final col (replaces scan1/23 + fill) -
// One block per bucket (~3.1k edges, 196 nodes): LDS count -> LDS scan ->
// rs writes -> LDS-cursor scatter into col. All atomics are LDS.

__global__ __launch_bounds__(256) void k_bucket(
    const int* __restrict__ sc, const int* __restrict__ bsumA,
    const int* __restrict__ ed, const int* __restrict__ es,
    int* __restrict__ rs, int* __restrict__ col) {
    __shared__ int sb[128];
    __shared__ int lcnt[NPB];
    __shared__ int s2[256];
    __shared__ int cur[NPB];
    int tid = threadIdx.x, b = blockIdx.x;
    if (tid < 128) sb[tid] = (tid < NSCB) ? bsumA[tid] : 0;
    __syncthreads();
    for (int off = 1; off < 128; off <<= 1) {
        int t = (tid < 128 && tid >= off) ? sb[tid - off] : 0;
        __syncthreads();
        if (tid < 128) sb[tid] += t;
        __syncthreads();
    }
    int L0 = b * NBLK;
    int i0 = L0 >> 10;
    int gstart = sc[L0] + (i0 ? sb[i0 - 1] : 0);
    int bend = N_EDGES;
    if (b + 1 < NBUK) {
        int L1 = (b + 1) * NBLK;
        int i1 = L1 >> 10;
        bend = sc[L1] + (i1 ? sb[i1 - 1] : 0);
    }
    if (tid < NPB) lcnt[tid] = 0;
    __syncthreads();
    for (int e = gstart + tid; e < bend; e += 256)
        atomicAdd(&lcnt[ed[e] - b * NPB], 1);  // LDS atomic
    __syncthreads();
    int v = (tid < NPB) ? lcnt[tid] : 0;
    s2[tid] = v;
    __syncthreads();
    for (int off = 1; off < 256; off <<= 1) {
        int t = (tid >= off) ? s2[tid - off] : 0;
        __syncthreads();
        s2[tid] += t;
        __syncthreads();
    }
    int excl = s2[tid] - v;
    int node = b * NPB + tid;
    if (tid < NPB) {
        if (node <= N_NODES) rs[node] = gstart + excl;
        cur[tid] = gstart + excl;
    }
    __syncthreads();
    for (int e = gstart + tid; e < bend; e += 256) {
        int p = atomicAdd(&cur[ed[e] - b * NPB], 1);  // LDS atomic
        col[p] = es[e];
    }
    if (b == NBUK - 1 && tid == 0) rs[N_NODES] = N_EDGES;
}

// ---------------- mean aggregation: one node per wave (validated r8) ------

#define ACCUM(v)                                                      \
    acc0 += bits2f((v).x << 16); acc1 += bits2f((v).x & 0xffff0000u); \
    acc2 += bits2f((v).y << 16); acc3 += bits2f((v).y & 0xffff0000u); \
    acc4 += bits2f((v).z << 16); acc5 += bits2f((v).z & 0xffff0000u); \
    acc6 += bits2f((v).w << 16); acc7 += bits2f((v).w & 0xffff0000u);

__global__ __launch_bounds__(256) void k_agg2(const unsigned short* __restrict__ h,
                                              const int* __restrict__ rs,
                                              const int* __restrict__ col,
                                              unsigned short* __restrict__ mean) {
    const int lane = threadIdx.x & 63;
    const int node = blockIdx.x * 4 + (threadIdx.x >> 6);
    if (node >= N_NODES) return;
    const int j0 = rs[node], j1 = rs[node + 1];
    const int deg = j1 - j0;
    const int q = lane >> 4;
    const int d8 = (lane & 15) * 8;

    int myc = (j0 + lane < j1) ? col[j0 + lane] : N_NODES;  // pad row: zeros
    const int nfull = deg < 64 ? deg : 64;
    const int nb = (nfull + 15) >> 4;   // wave-uniform batch count

    float acc0 = 0.f, acc1 = 0.f, acc2 = 0.f, acc3 = 0.f;
    float acc4 = 0.f, acc5 = 0.f, acc6 = 0.f, acc7 = 0.f;

    for (int i = 0; i < nb; ++i) {      // uniform trips: shfl always safe
        int t = (i << 4) + q;
        int c0 = __shfl(myc, t, 64);
        int c1 = __shfl(myc, t + 4, 64);
        int c2 = __shfl(myc, t + 8, 64);
        int c3 = __shfl(myc, t + 12, 64);
        uint4 v0 = *(const uint4*)(h + (size_t)c0 * D + d8);
        uint4 v1 = *(const uint4*)(h + (size_t)c1 * D + d8);
        uint4 v2 = *(const uint4*)(h + (size_t)c2 * D + d8);
        uint4 v3 = *(const uint4*)(h + (size_t)c3 * D + d8);
        ACCUM(v0); ACCUM(v1); ACCUM(v2); ACCUM(v3);
    }
    for (int j = j0 + 64 + q; j < j1; j += 4) {  // deg>64 (~never); no shfl
        int c = col[j];
        uint4 v = *(const uint4*)(h + (size_t)c * D + d8);
        ACCUM(v);
    }

    acc0 += __shfl_xor(acc0, 16, 64); acc0 += __shfl_xor(acc0, 32, 64);
    acc1 += __shfl_xor(acc1, 16, 64); acc1 += __shfl_xor(acc1, 32, 64);
    acc2 += __shfl_xor(acc2, 16, 64); acc2 += __shfl_xor(acc2, 32, 64);
    acc3 += __shfl_xor(acc3, 16, 64); acc3 += __shfl_xor(acc3, 32, 64);
    acc4 += __shfl_xor(acc4, 16, 64); acc4 += __shfl_xor(acc4, 32, 64);
    acc5 += __shfl_xor(acc5, 16, 64); acc5 += __shfl_xor(acc5, 32, 64);
    acc6 += __shfl_xor(acc6, 16, 64); acc6 += __shfl_xor(acc6, 32, 64);
    acc7 += __shfl_xor(acc7, 16, 64); acc7 += __shfl_xor(acc7, 32, 64);

    if (lane < 16) {
        float s = 1.0f / (float)(deg > 0 ? deg : 1);
        uint4 o;
        o.x = (unsigned int)f2b(acc0 * s) | ((unsigned int)f2b(acc1 * s) << 16);
        o.y = (unsigned int)f2b(acc2 * s) | ((unsigned int)f2b(acc3 * s) << 16);
        o.z = (unsigned int)f2b(acc4 * s) | ((unsigned int)f2b(acc5 * s) << 16);
        o.w = (unsigned int)f2b(acc6 * s) | ((unsigned int)f2b(acc7 * s) << 16);
        *reinterpret_cast<uint4*>(mean + (size_t)node * D + d8) = o;
    }
}

// ---------------- MFMA GEMM (relu, layer 0): 2 row-groups per wave --------

__global__ __launch_bounds__(256) void k_gemm(
    const unsigned short* __restrict__ Amean, const unsigned short* __restrict__ Ah,
    const unsigned short* __restrict__ Bp, const float* __restrict__ bias,
    unsigned short* __restrict__ outh) {
    int lane = threadIdx.x & 63;
    int w = blockIdx.x * 4 + (threadIdx.x >> 6);
    int g0 = w * 2;
    if (g0 >= NGROUPS) return;
    int g1ok = (g0 + 1 < NGROUPS);
    int hl = lane & 15;
    int klane = (lane >> 4) * 8;
    int arow0 = g0 * 16 + hl;
    int arow1 = g0 * 16 + 16 + hl;
    if (arow1 > N_NODES) arow1 = N_NODES;  // pad row (zeros) when g1 invalid

    f32x4 acc0[8], acc1[8];
    #pragma unroll
    for (int i = 0; i < 8; ++i) { acc0[i] = (f32x4)0.0f; acc1[i] = (f32x4)0.0f; }

    const short8* bpv = reinterpret_cast<const short8*>(Bp);
    #pragma unroll
    for (int kstep = 0; kstep < 8; ++kstep) {
        const unsigned short* Asrc = (kstep < 4) ? Amean : Ah;
        int kk = (kstep & 3) * 32 + klane;
        short8 a0 = *reinterpret_cast<const short8*>(Asrc + (size_t)arow0 * D + kk);
        short8 a1 = *reinterpret_cast<const short8*>(Asrc + (size_t)arow1 * D + kk);
        #pragma unroll
        for (int cf = 0; cf < 8; ++cf) {
            short8 b = bpv[(kstep * 8 + cf) * 64 + lane];
            acc0[cf] = __builtin_amdgcn_mfma_f32_16x16x32_bf16(a0, b, acc0[cf], 0, 0, 0);
            acc1[cf] = __builtin_amdgcn_mfma_f32_16x16x32_bf16(a1, b, acc1[cf], 0, 0, 0);
        }
    }

    int rbase0 = g0 * 16 + (lane >> 4) * 4;
    #pragma unroll
    for (int cf = 0; cf < 8; ++cf) {
        int bcol = cf * 16 + hl;
        float bv = bias[bcol];
        #pragma unroll
        for (int i = 0; i < 4; ++i) {
            float v = fmaxf(acc0[cf][i] + bv, 0.f);
            outh[(size_t)(rbase0 + i) * D + bcol] = f2b(v);
            if (g1ok) {
                float v1 = fmaxf(acc1[cf][i] + bv, 0.f);
                outh[(size_t)(rbase0 + 16 + i) * D + bcol] = f2b(v1);
            }
        }
    }
}

// ---- MFMA GEMM layer 1 + fused dot: s = relu(row).u, t = relu(row).v -----

__global__ __launch_bounds__(256) void k_gemm_dot(
    const unsigned short* __restrict__ Amean, const unsigned short* __restrict__ Ah,
    const unsigned short* __restrict__ Bp, const float* __restrict__ bias,
    const float* __restrict__ uvc, float* __restrict__ s, float* __restrict__ t) {
    int lane = threadIdx.x & 63;
    int w = blockIdx.x * 4 + (threadIdx.x >> 6);
    int g0 = w * 2;
    if (g0 >= NGROUPS) return;
    int g1ok = (g0 + 1 < NGROUPS);
    int hl = lane & 15;
    int klane = (lane >> 4) * 8;
    int arow0 = g0 * 16 + hl;
    int arow1 = g0 * 16 + 16 + hl;
    if (arow1 > N_NODES) arow1 = N_NODES;

    f32x4 acc0[8], acc1[8];
    #pragma unroll
    for (int i = 0; i < 8; ++i) { acc0[i] = (f32x4)0.0f; acc1[i] = (f32x4)0.0f; }

    const short8* bpv = reinterpret_cast<const short8*>(Bp);
    #pragma unroll
    for (int kstep = 0; kstep < 8; ++kstep) {
        const unsigned short* Asrc = (kstep < 4) ? Amean : Ah;
        int kk = (kstep & 3) * 32 + klane;
        short8 a0 = *reinterpret_cast<const short8*>(Asrc + (size_t)arow0 * D + kk);
        short8 a1 = *reinterpret_cast<const short8*>(Asrc + (size_t)arow1 * D + kk);
        #pragma unroll
        for (int cf = 0; cf < 8; ++cf) {
            short8 b = bpv[(kstep * 8 + cf) * 64 + lane];
            acc0[cf] = __builtin_amdgcn_mfma_f32_16x16x32_bf16(a0, b, acc0[cf], 0, 0, 0);
            acc1[cf] = __builtin_amdgcn_mfma_f32_16x16x32_bf16(a1, b, acc1[cf], 0, 0, 0);
        }
    }

    float ps0[4] = {0.f, 0.f, 0.f, 0.f}, pt0[4] = {0.f, 0.f, 0.f, 0.f};
    float ps1[4] = {0.f, 0.f, 0.f, 0.f}, pt1[4] = {0.f, 0.f, 0.f, 0.f};
    #pragma unroll
    for (int cf = 0; cf < 8; ++cf) {
        int bcol = cf * 16 + hl;
        float bv = bias[bcol];
        float uu = uvc[bcol];
        float vv = uvc[128 + bcol];
        #pragma unroll
        for (int i = 0; i < 4; ++i) {
            float v = fmaxf(acc0[cf][i] + bv, 0.f);
            ps0[i] += v * uu;
            pt0[i] += v * vv;
            float v1 = fmaxf(acc1[cf][i] + bv, 0.f);
            ps1[i] += v1 * uu;
            pt1[i] += v1 * vv;
        }
    }
    #pragma unroll
    for (int m = 1; m < 16; m <<= 1) {
        #pragma unroll
        for (int i = 0; i < 4; ++i) {
            ps0[i] += __shfl_xor(ps0[i], m, 64);
            pt0[i] += __shfl_xor(pt0[i], m, 64);
            ps1[i] += __shfl_xor(ps1[i], m, 64);
            pt1[i] += __shfl_xor(pt1[i], m, 64);
        }
    }
    if (hl == 0) {
        int rbase0 = g0 * 16 + (lane >> 4) * 4;
        #pragma unroll
        for (int i = 0; i < 4; ++i) {
            s[rbase0 + i] = ps0[i];
            t[rbase0 + i] = pt0[i];
            if (g1ok) {
                s[rbase0 + 16 + i] = ps1[i];
                t[rbase0 + 16 + i] = pt1[i];
            }
        }
    }
}

// scalar mean-gather epilogue: out[i] = mean_j s[col] + t[i] + c
__global__ __launch_bounds__(256) void k_sagg2(const float* __restrict__ s,
                                               const float* __restrict__ t,
                                               const float* __restrict__ uvc,
                                               const int* __restrict__ rs,
                                               const int* __restrict__ col,
                                               float* __restrict__ out) {
    const int lane = threadIdx.x & 63;
    const int hl = lane & 15;
    const int node = blockIdx.x * 16 + (threadIdx.x >> 6) * 4 + (lane >> 4);
    const int j0 = rs[node], j1 = rs[node + 1];
    float sm = 0.f;
    for (int j = j0 + hl; j < j1; j += 16) sm += s[col[j]];
    #pragma unroll
    for (int m = 1; m < 16; m <<= 1) sm += __shfl_xor(sm, m, 64);
    if (hl == 0) {
        int deg = j1 - j0;
        out[node] = sm / (float)(deg > 0 ? deg : 1) + t[node] + uvc[256];
    }
}

// ---------------- launch ----------------

extern "C" void kernel_launch(void* const* d_in, const int* in_sizes, int n_in,
                              void* d_out, int out_size, void* d_ws,
                              size_t ws_size, hipStream_t stream) {
    const float* x = (const float*)d_in[0];
    const int* ei = (const int*)d_in[1];
    const int* src = ei;
    const int* dst = ei + N_EDGES;
    const float* wn[3] = {(const float*)d_in[2], (const float*)d_in[5],
                          (const float*)d_in[8]};
    const float* wr[3] = {(const float*)d_in[3], (const float*)d_in[6],
                          (const float*)d_in[9]};
    const float* bs[3] = {(const float*)d_in[4], (const float*)d_in[7],
                          (const float*)d_in[10]};
    const float* wc = (const float*)d_in[11];
    const float* bc = (const float*)d_in[12];
    float* out = (float*)d_out;

    char* ws = (char*)d_ws;
    size_t off = 0;
    auto alloc = [&](size_t bytes) -> void* {
        void* p = (void*)(ws + off);
        off += (bytes + 255) & ~(size_t)255;
        return p;
    };
    const size_t frows = (size_t)(N_NODES + 1) * D;
    int* cnt = (int*)alloc((size_t)LTOT * 4);      // [NBLK][NBUK]
    int* sc = (int*)alloc((size_t)LTOT * 4);       // scanned cells
    int* bsumA = (int*)alloc(128 * 4);
    int* ed = (int*)alloc(N_EDGES * 4);            // bucket-grouped dst
    int* es = (int*)alloc(N_EDGES * 4);            // bucket-grouped src
    int* rs = (int*)alloc((N_NODES + 1) * 4);
    int* col = (int*)alloc(N_EDGES * 4);
    unsigned short* f0 = (unsigned short*)alloc(frows * 2);
    unsigned short* f1 = (unsigned short*)alloc(frows * 2);
    unsigned short* f2 = (unsigned short*)alloc(frows * 2);
    unsigned short* Bp = (unsigned short*)alloc(2 * 256 * 128 * 2);
    float* uvc = (float*)alloc(260 * 4);
    float* sbuf = (float*)alloc(N_NODES * 4);
    float* tbuf = (float*)alloc(N_NODES * 4);

    // no memsets needed: cnt fully written by k_big, LDS counters zeroed in-kernel

    k_big<<<6675, 256, 0, stream>>>(dst, cnt, x, wn[0], wr[0], wn[1], wr[1],
                                    wn[2], wr[2], bs[2], wc, bc,
                                    f0, f1, f2, Bp, uvc);
    k_scanA<<<NSCB, 1024, 0, stream>>>(cnt, sc, bsumA);
    k_scatter<<<NBLK, 256, 0, stream>>>(src, dst, sc, bsumA, ed, es);
    k_bucket<<<NBUK, 256, 0, stream>>>(sc, bsumA, ed, es, rs, col);

    const int agg_grid = (N_NODES + 3) / 4;
    const int gemm_grid = ((NGROUPS + 1) / 2 + 3) / 4;
    unsigned short* Bp0 = Bp;
    unsigned short* Bp1 = Bp + 256 * 128;

    // layer 0: in=f0, mean=f1, out=f2 (relu)
    k_agg2<<<agg_grid, 256, 0, stream>>>(f0, rs, col, f1);
    k_gemm<<<gemm_grid, 256, 0, stream>>>(f1, f0, Bp0, bs[0], f2);
    // layer 1 (+ fused layer-2 dots): in=f2, mean=f0 -> s,t directly
    k_agg2<<<agg_grid, 256, 0, stream>>>(f2, rs, col, f0);
    k_gemm_dot<<<gemm_grid, 256, 0, stream>>>(f0, f2, Bp1, bs[1], uvc, sbuf,
                                              tbuf);
    // collapsed layer 2 + classifier: out = mean(s) + t + c
    k_sagg2<<<NGROUPS, 256, 0, stream>>>(sbuf, tbuf, uvc, rs, col, out);
}